// Round 3
// baseline (1478.288 us; speedup 1.0000x reference)
//
#include <hip/hip_runtime.h>
#include <hip/hip_bf16.h>
#include <cstdint>
#include <cstddef>

#define T_DIM 8
#define N_NODES 50000
#define F_DIM 64
#define H_DIM 32
#define L_DIM 64
#define E_EDGES 800000

#define NB 128            // dst bins per t
#define NPB 391           // nodes per bin (128*391 = 50048 >= 50000)
#define BIN_CAP 8192      // >= 6250 mean + 24 sigma
#define CHUNK_A 16000     // edges per k_part block (50 blocks per t)

__device__ __forceinline__ unsigned short f2bf(float f) {
  unsigned u = __float_as_uint(f);
  u = u + 0x7FFFu + ((u >> 16) & 1u);   // round-to-nearest-even
  return (unsigned short)(u >> 16);
}
__device__ __forceinline__ float bf2f(unsigned short b) {
  return __uint_as_float(((unsigned)b) << 16);
}

// K1: radix-partition edges into 128 dst-bins per t (packed (dl<<16)|src),
// and count deg. Two-pass per block: LDS histogram -> one global atomic per
// bin per block for base -> scatter. Writes are append-runs (~125 entries per
// bin per block): hot dirty window ~8KB/block, so HBM write = 25.6MB once
// (R1's CSR scatter wrote 418MB due to line-fill eviction).
__global__ void k_part(const int* __restrict__ ei, int* __restrict__ deg,
                       int* __restrict__ bincur, int* __restrict__ binbuf) {
  int t = blockIdx.y;
  int e0 = blockIdx.x * CHUNK_A;
  const int* dstp = ei + (size_t)(t * 2 + 1) * E_EDGES;
  const int* srcp = ei + (size_t)(t * 2 + 0) * E_EDGES;
  __shared__ int hist[NB], bbase[NB];
  int tid = threadIdx.x;
  for (int i = tid; i < NB; i += 256) hist[i] = 0;
  __syncthreads();
  const int4* d4 = reinterpret_cast<const int4*>(dstp + e0);
  const int4* s4 = reinterpret_cast<const int4*>(srcp + e0);
  // pass 1: LDS histogram + global deg count
  for (int q = tid; q < CHUNK_A / 4; q += 256) {
    int4 d = d4[q];
    #pragma unroll
    for (int k = 0; k < 4; ++k) {
      int dst = (k == 0) ? d.x : (k == 1) ? d.y : (k == 2) ? d.z : d.w;
      atomicAdd(&hist[dst / NPB], 1);
      atomicAdd(&deg[t * N_NODES + dst], 1);
    }
  }
  __syncthreads();
  for (int i = tid; i < NB; i += 256) {
    int c = hist[i];
    bbase[i] = atomicAdd(&bincur[t * NB + i], c);
    hist[i] = 0;
  }
  __syncthreads();
  // pass 2: scatter packed words (chunk re-read hits L2)
  for (int q = tid; q < CHUNK_A / 4; q += 256) {
    int4 d = d4[q];
    int4 s = s4[q];
    #pragma unroll
    for (int k = 0; k < 4; ++k) {
      int dst = (k == 0) ? d.x : (k == 1) ? d.y : (k == 2) ? d.z : d.w;
      int src = (k == 0) ? s.x : (k == 1) ? s.y : (k == 2) ? s.z : s.w;
      int b = dst / NPB;
      int dl = dst - b * NPB;
      int off = bbase[b] + atomicAdd(&hist[b], 1);
      if (off < BIN_CAP)
        binbuf[(size_t)(t * NB + b) * BIN_CAP + off] = (dl << 16) | src;
    }
  }
}

// K2: s[t][n][:] = rsqrt(deg+1) * (x[t][n][:] @ conv_w), stored bf16
__global__ void k_xw(const float* __restrict__ x, const float* __restrict__ w,
                     const int* __restrict__ deg, unsigned short* __restrict__ s) {
  int t = blockIdx.y;
  int n = blockIdx.x * 256 + threadIdx.x;
  if (n >= N_NODES) return;
  const float4* xr = reinterpret_cast<const float4*>(x + ((size_t)t * N_NODES + n) * F_DIM);
  const float4* w4 = reinterpret_cast<const float4*>(w);
  float4 acc[8];
  #pragma unroll
  for (int h = 0; h < 8; ++h) acc[h] = make_float4(0.f, 0.f, 0.f, 0.f);
  for (int k4 = 0; k4 < 16; ++k4) {
    float4 xv = xr[k4];
    #pragma unroll
    for (int kk = 0; kk < 4; ++kk) {
      float xs = (kk == 0) ? xv.x : (kk == 1) ? xv.y : (kk == 2) ? xv.z : xv.w;
      #pragma unroll
      for (int h = 0; h < 8; ++h) {
        float4 wv = w4[(k4 * 4 + kk) * 8 + h];   // wave-uniform -> scalar loads
        acc[h].x += xs * wv.x; acc[h].y += xs * wv.y;
        acc[h].z += xs * wv.z; acc[h].w += xs * wv.w;
      }
    }
  }
  float dinv = rsqrtf((float)(deg[t * N_NODES + n] + 1));
  unsigned short* srow = s + ((size_t)t * N_NODES + n) * H_DIM;
  #pragma unroll
  for (int h = 0; h < 8; ++h) {
    uint2 u;
    u.x = (unsigned)f2bf(acc[h].x * dinv) | ((unsigned)f2bf(acc[h].y * dinv) << 16);
    u.y = (unsigned)f2bf(acc[h].z * dinv) | ((unsigned)f2bf(acc[h].w * dinv) << 16);
    *reinterpret_cast<uint2*>(srow + h * 4) = u;
  }
}

// K3: per-(t,bin) aggregation. LDS f32 acc[32][391] (feature-major: stride
// 391 % 32 == 7 spreads banks). 8 lanes per edge gather the 64B s[src] row and
// LDS-atomic-add. Epilogue fuses self-loop + dinv + bias + relu + node-pool.
__global__ void k_agg(const unsigned short* __restrict__ s, const int* __restrict__ binbuf,
                      const int* __restrict__ bincur, const int* __restrict__ deg,
                      const float* __restrict__ conv_b, float* __restrict__ partials) {
  int b = blockIdx.x, t = blockIdx.y;
  __shared__ float acc[H_DIM][NPB];       // 50048 B
  __shared__ float red[4][H_DIM];
  int tid = threadIdx.x;
  float* af = &acc[0][0];
  for (int i = tid; i < H_DIM * NPB; i += 256) af[i] = 0.f;
  __syncthreads();
  int cnt = bincur[t * NB + b];
  if (cnt > BIN_CAP) cnt = BIN_CAP;
  const int* buf = binbuf + (size_t)(t * NB + b) * BIN_CAP;
  const unsigned short* sbase = s + (size_t)t * N_NODES * H_DIM;
  int g = tid >> 3, j = tid & 7;          // 32 edges/iter, lane j -> features 4j..4j+3
  for (int base = 0; base < cnt; base += 32) {
    int idx = base + g;
    if (idx < cnt) {
      int wd = buf[idx];
      int src = wd & 0xFFFF;
      int dl = wd >> 16;
      if (dl < NPB && src < N_NODES) {
        ushort4 v = *reinterpret_cast<const ushort4*>(sbase + (size_t)src * H_DIM + j * 4);
        atomicAdd(&acc[4 * j + 0][dl], bf2f(v.x));
        atomicAdd(&acc[4 * j + 1][dl], bf2f(v.y));
        atomicAdd(&acc[4 * j + 2][dl], bf2f(v.z));
        atomicAdd(&acc[4 * j + 3][dl], bf2f(v.w));
      }
    }
  }
  __syncthreads();
  // epilogue: thread (f = tid&31, dl-slice = tid>>5)
  int f = tid & 31, dg = tid >> 5;
  float bf = conv_b[f];
  float pool = 0.f;
  for (int dl = dg; dl < NPB; dl += 8) {
    int n = b * NPB + dl;
    if (n < N_NODES) {
      float self = bf2f(sbase[(size_t)n * H_DIM + f]);
      float dinv = rsqrtf((float)(deg[t * N_NODES + n] + 1));
      float v = dinv * (acc[f][dl] + self) + bf;
      pool += fmaxf(v, 0.f);
    }
  }
  pool += __shfl_xor(pool, 32, 64);       // combine the two dl-groups in a wave
  int wid = tid >> 6, lane = tid & 63;
  if (lane < 32) red[wid][lane] = pool;
  __syncthreads();
  if (tid < 32) {
    float sm = red[0][tid] + red[1][tid] + red[2][tid] + red[3][tid];
    partials[((size_t)t * NB + b) * H_DIM + tid] = sm;
  }
}

// K4: reduce per-bin partials -> pooled node-sum per (t,h)
__global__ void k_reduce(const float* __restrict__ partials, float* __restrict__ seq_raw,
                         int nblk) {
  int t = blockIdx.x;
  int tid = threadIdx.x;           // 256
  int h = tid & 31, w = tid >> 5;  // 8 slices
  float sum = 0.f;
  for (int b = w; b < nblk; b += 8) sum += partials[((size_t)t * nblk + b) * H_DIM + h];
  __shared__ float red[8][32];
  red[w][h] = sum;
  __syncthreads();
  if (tid < 32) {
    float sm = 0.f;
    #pragma unroll
    for (int i = 0; i < 8; ++i) sm += red[i][tid];
    seq_raw[t * H_DIM + tid] = sm;
  }
}

// K5a: precompute per-t x-part of LSTM gates
__global__ void k_gatex(const float* __restrict__ seq_raw, const float* __restrict__ w_ih,
                        const float* __restrict__ b_ih, const float* __restrict__ b_hh,
                        float* __restrict__ gx) {
  int t = blockIdx.x;
  int j = threadIdx.x;  // 256
  __shared__ float xb[32];
  if (j < 32) xb[j] = seq_raw[t * H_DIM + j] * (1.0f / (float)N_NODES);
  __syncthreads();
  float g = b_ih[j] + b_hh[j];
  #pragma unroll
  for (int k = 0; k < 32; ++k) g += w_ih[j * 32 + k] * xb[k];
  gx[t * 256 + j] = g;
}

// K5b: sequential LSTM (8 steps) + fc head. Single block.
__global__ void k_lstm(const float* __restrict__ gx, const float* __restrict__ w_hh,
                       const float* __restrict__ fc_w, const float* __restrict__ fc_b,
                       float* __restrict__ out) {
  __shared__ float hbuf[64], cbuf[64], gates[256];
  int j = threadIdx.x;  // 256
  if (j < 64) { hbuf[j] = 0.f; cbuf[j] = 0.f; }
  __syncthreads();
  for (int t = 0; t < T_DIM; ++t) {
    float g = gx[t * 256 + j];
    #pragma unroll 8
    for (int k = 0; k < 64; ++k) g += w_hh[j * 64 + k] * hbuf[k];
    gates[j] = g;
    __syncthreads();
    if (j < 64) {
      float ii = 1.f / (1.f + expf(-gates[j]));
      float ff = 1.f / (1.f + expf(-gates[64 + j]));
      float gg = tanhf(gates[128 + j]);
      float oo = 1.f / (1.f + expf(-gates[192 + j]));
      float c = ff * cbuf[j] + ii * gg;
      cbuf[j] = c;
      hbuf[j] = oo * tanhf(c);
    }
    __syncthreads();
  }
  if (j == 0) {
    float acc = 0.f;
    for (int k = 0; k < 64; ++k) acc += hbuf[k] * fc_w[k];
    out[0] = acc + fc_b[0];
  }
}

extern "C" void kernel_launch(void* const* d_in, const int* in_sizes, int n_in,
                              void* d_out, int out_size, void* d_ws, size_t ws_size,
                              hipStream_t stream) {
  const float* x      = (const float*)d_in[0];
  const int*   ei     = (const int*)  d_in[1];
  const float* conv_w = (const float*)d_in[2];
  const float* conv_b = (const float*)d_in[3];
  const float* w_ih   = (const float*)d_in[4];
  const float* w_hh   = (const float*)d_in[5];
  const float* b_ih   = (const float*)d_in[6];
  const float* b_hh   = (const float*)d_in[7];
  const float* fc_w   = (const float*)d_in[8];
  const float* fc_b   = (const float*)d_in[9];
  float* out = (float*)d_out;

  char* wsb = (char*)d_ws;
  size_t off = 0;
  auto alloc = [&](size_t bytes) {
    void* p = wsb + off;
    off = (off + bytes + 255) & ~(size_t)255;
    return p;
  };
  int* deg      = (int*)alloc(sizeof(int) * T_DIM * N_NODES);            // 1.6 MB
  int* bincur   = (int*)alloc(sizeof(int) * T_DIM * NB);                 // 4 KB (contiguous after deg)
  int* binbuf   = (int*)alloc(sizeof(int) * (size_t)T_DIM * NB * BIN_CAP); // 32 MB
  unsigned short* s = (unsigned short*)alloc(sizeof(unsigned short) * (size_t)T_DIM * N_NODES * H_DIM); // 25.6 MB
  float* partials = (float*)alloc(sizeof(float) * (size_t)T_DIM * NB * H_DIM);
  float* seq_raw  = (float*)alloc(sizeof(float) * T_DIM * H_DIM);
  float* gx       = (float*)alloc(sizeof(float) * T_DIM * 256);

  hipMemsetAsync(deg, 0, sizeof(int) * T_DIM * N_NODES, stream);
  hipMemsetAsync(bincur, 0, sizeof(int) * T_DIM * NB, stream);

  dim3 gA(E_EDGES / CHUNK_A, T_DIM);      // 50 x 8
  k_part<<<gA, 256, 0, stream>>>(ei, deg, bincur, binbuf);
  dim3 g4((N_NODES + 255) / 256, T_DIM);
  k_xw<<<g4, 256, 0, stream>>>(x, conv_w, deg, s);
  dim3 gB(NB, T_DIM);                     // 128 x 8
  k_agg<<<gB, 256, 0, stream>>>(s, binbuf, bincur, deg, conv_b, partials);
  k_reduce<<<T_DIM, 256, 0, stream>>>(partials, seq_raw, NB);
  k_gatex<<<T_DIM, 256, 0, stream>>>(seq_raw, w_ih, b_ih, b_hh, gx);
  k_lstm<<<1, 256, 0, stream>>>(gx, w_hh, fc_w, fc_b, out);
}

// Round 5
// 349.765 us; speedup vs baseline: 4.2265x; 4.2265x over previous
//
#include <hip/hip_runtime.h>
#include <hip/hip_bf16.h>
#include <cstdint>
#include <cstddef>

#define T_DIM 8
#define N_NODES 50000
#define F_DIM 64
#define H_DIM 32
#define L_DIM 64
#define E_EDGES 800000

#define NB 128            // dst bins per t
#define NPB 391           // nodes per bin (128*391 = 50048 >= 50000)
#define BIN_CAP 8192      // mean 6250 + 24 sigma
#define CHUNK_A 16000     // edges per k_part block (50 blocks per t)
#define NBLK_G 1563       // ceil(N_NODES/32) node-groups per t

__device__ __forceinline__ unsigned short f2bf(float f) {
  unsigned u = __float_as_uint(f);
  u = u + 0x7FFFu + ((u >> 16) & 1u);   // round-to-nearest-even
  return (unsigned short)(u >> 16);
}
__device__ __forceinline__ float bf2f(unsigned short b) {
  return __uint_as_float(((unsigned)b) << 16);
}

// K1: radix-partition edges into 128 dst-bins per t, packed (dl<<16)|src.
// LDS histogram -> one global atomic per bin per block -> append-run scatter
// (hot dirty window ~8KB/block so writes coalesce into full lines).
__global__ void k_part(const int* __restrict__ ei, int* __restrict__ bincur,
                       int* __restrict__ binbuf) {
  int t = blockIdx.y;
  int e0 = blockIdx.x * CHUNK_A;
  const int* dstp = ei + (size_t)(t * 2 + 1) * E_EDGES;
  const int* srcp = ei + (size_t)(t * 2 + 0) * E_EDGES;
  __shared__ int hist[NB], bbase[NB];
  int tid = threadIdx.x;
  for (int i = tid; i < NB; i += 256) hist[i] = 0;
  __syncthreads();
  const int4* d4 = reinterpret_cast<const int4*>(dstp + e0);
  const int4* s4 = reinterpret_cast<const int4*>(srcp + e0);
  for (int q = tid; q < CHUNK_A / 4; q += 256) {
    int4 d = d4[q];
    #pragma unroll
    for (int k = 0; k < 4; ++k) {
      int dst = (k == 0) ? d.x : (k == 1) ? d.y : (k == 2) ? d.z : d.w;
      atomicAdd(&hist[dst / NPB], 1);
    }
  }
  __syncthreads();
  for (int i = tid; i < NB; i += 256) {
    int c = hist[i];
    bbase[i] = atomicAdd(&bincur[t * NB + i], c);
    hist[i] = 0;
  }
  __syncthreads();
  for (int q = tid; q < CHUNK_A / 4; q += 256) {
    int4 d = d4[q];     // L2-hot re-read
    int4 s = s4[q];
    #pragma unroll
    for (int k = 0; k < 4; ++k) {
      int dst = (k == 0) ? d.x : (k == 1) ? d.y : (k == 2) ? d.z : d.w;
      int src = (k == 0) ? s.x : (k == 1) ? s.y : (k == 2) ? s.z : s.w;
      int b = dst / NPB;
      int dl = dst - b * NPB;
      int off = bbase[b] + atomicAdd(&hist[b], 1);
      if (off < BIN_CAP)
        binbuf[(size_t)(t * NB + b) * BIN_CAP + off] = (dl << 16) | src;
    }
  }
}

// K2: per-(t,bin) finalize: stage segment in LDS, per-node histogram (-> deg),
// block scan (-> rowg offsets), counting-sort segment in place by local node.
// Kills the global-atomic deg count, the global scan, and the CSR scatter.
__global__ void k_degfill(const int* __restrict__ bincur, int* __restrict__ binbuf,
                          int* __restrict__ deg, int* __restrict__ rowg) {
  int b = blockIdx.x & (NB - 1);
  int t = blockIdx.x >> 7;
  __shared__ int stage[BIN_CAP];        // 32KB
  __shared__ int hist[NPB], rowoff[NPB + 1];
  __shared__ int wsum[4];
  int tid = threadIdx.x;
  int cnt = bincur[t * NB + b];
  if (cnt > BIN_CAP) cnt = BIN_CAP;
  int* gbuf = binbuf + (size_t)(t * NB + b) * BIN_CAP;
  for (int i = tid; i < cnt; i += 256) stage[i] = gbuf[i];
  for (int i = tid; i < NPB; i += 256) hist[i] = 0;
  __syncthreads();
  for (int i = tid; i < cnt; i += 256) atomicAdd(&hist[stage[i] >> 16], 1);
  __syncthreads();
  int nb0 = b * NPB;
  for (int dl = tid; dl < NPB; dl += 256) {
    int n = nb0 + dl;
    if (n < N_NODES) deg[t * N_NODES + n] = hist[dl];
  }
  // block exclusive scan of hist[0..NPB)
  int i0 = 2 * tid, i1 = 2 * tid + 1;
  int a0 = (i0 < NPB) ? hist[i0] : 0;
  int a1 = (i1 < NPB) ? hist[i1] : 0;
  int tsum = a0 + a1;
  int lane = tid & 63, wid = tid >> 6;
  int sc = tsum;
  #pragma unroll
  for (int off = 1; off < 64; off <<= 1) {
    int o = __shfl_up(sc, off, 64);
    if (lane >= off) sc += o;
  }
  if (lane == 63) wsum[wid] = sc;
  __syncthreads();
  if (tid == 0) {
    int c = 0;
    for (int k = 0; k < 4; ++k) { int v = wsum[k]; wsum[k] = c; c += v; }
  }
  __syncthreads();
  int excl = wsum[wid] + (sc - tsum);
  if (i0 < NPB) rowoff[i0] = excl;
  if (i1 < NPB) rowoff[i1] = excl + a0;
  if (tid == 0) rowoff[NPB] = cnt;
  __syncthreads();
  int* rg = rowg + (size_t)(t * NB + b) * (NPB + 1);
  for (int i = tid; i <= NPB; i += 256) rg[i] = rowoff[i];
  for (int i = tid; i < NPB; i += 256) hist[i] = 0;   // reuse as cursor
  __syncthreads();
  for (int i = tid; i < cnt; i += 256) {
    int w = stage[i];
    int dl = w >> 16;
    int pos = rowoff[dl] + atomicAdd(&hist[dl], 1);
    gbuf[pos] = w & 0xFFFF;           // src only, sorted by local node
  }
}

// K3: s[t][n][:] = rsqrt(deg+1) * (x[t][n][:] @ conv_w), stored bf16
__global__ void k_xw(const float* __restrict__ x, const float* __restrict__ w,
                     const int* __restrict__ deg, unsigned short* __restrict__ s) {
  int t = blockIdx.y;
  int n = blockIdx.x * 256 + threadIdx.x;
  if (n >= N_NODES) return;
  const float4* xr = reinterpret_cast<const float4*>(x + ((size_t)t * N_NODES + n) * F_DIM);
  const float4* w4 = reinterpret_cast<const float4*>(w);
  float4 acc[8];
  #pragma unroll
  for (int h = 0; h < 8; ++h) acc[h] = make_float4(0.f, 0.f, 0.f, 0.f);
  for (int k4 = 0; k4 < 16; ++k4) {
    float4 xv = xr[k4];
    #pragma unroll
    for (int kk = 0; kk < 4; ++kk) {
      float xs = (kk == 0) ? xv.x : (kk == 1) ? xv.y : (kk == 2) ? xv.z : xv.w;
      #pragma unroll
      for (int h = 0; h < 8; ++h) {
        float4 wv = w4[(k4 * 4 + kk) * 8 + h];   // wave-uniform -> scalar loads
        acc[h].x += xs * wv.x; acc[h].y += xs * wv.y;
        acc[h].z += xs * wv.z; acc[h].w += xs * wv.w;
      }
    }
  }
  float dinv = rsqrtf((float)(deg[t * N_NODES + n] + 1));
  unsigned short* srow = s + ((size_t)t * N_NODES + n) * H_DIM;
  #pragma unroll
  for (int h = 0; h < 8; ++h) {
    uint2 u;
    u.x = (unsigned)f2bf(acc[h].x * dinv) | ((unsigned)f2bf(acc[h].y * dinv) << 16);
    u.y = (unsigned)f2bf(acc[h].z * dinv) | ((unsigned)f2bf(acc[h].w * dinv) << 16);
    *reinterpret_cast<uint2*>(srow + h * 4) = u;
  }
}

// K4: atomic-free per-node gather via rowg. t = bid&7 pins each t to one XCD
// (round-robin dispatch) so the 3.2MB per-t s-slice stays L2-resident.
__global__ void k_gather2(const unsigned short* __restrict__ s, const int* __restrict__ binsrt,
                          const int* __restrict__ rowg, const float* __restrict__ conv_b,
                          float* __restrict__ partials) {
  int bid = blockIdx.x;
  int t = bid & 7;
  int gblk = bid >> 3;                  // 0..NBLK_G-1
  int tid = threadIdx.x;
  int g = tid >> 3, j = tid & 7;        // 32 nodes x 8 feature-lanes
  int n = gblk * 32 + g;
  float4 val = make_float4(0.f, 0.f, 0.f, 0.f);
  if (n < N_NODES) {
    int b = n / NPB, dl = n - b * NPB;
    const int* ro = rowg + (size_t)(t * NB + b) * (NPB + 1);
    int start = ro[dl], end = ro[dl + 1];
    float dinv = rsqrtf((float)(end - start + 1));
    const unsigned short* sbase = s + (size_t)t * N_NODES * H_DIM;
    ushort4 u = *reinterpret_cast<const ushort4*>(sbase + (size_t)n * H_DIM + j * 4);
    float4 acc = make_float4(bf2f(u.x), bf2f(u.y), bf2f(u.z), bf2f(u.w));
    const int* col = binsrt + (size_t)(t * NB + b) * BIN_CAP;
    for (int p = start; p < end; ++p) {
      int c = col[p];                   // broadcast across the 8 lanes
      ushort4 v = *reinterpret_cast<const ushort4*>(sbase + (size_t)c * H_DIM + j * 4);
      acc.x += bf2f(v.x); acc.y += bf2f(v.y); acc.z += bf2f(v.z); acc.w += bf2f(v.w);
    }
    const float4 bb = reinterpret_cast<const float4*>(conv_b)[j];
    val.x = fmaxf(acc.x * dinv + bb.x, 0.f);
    val.y = fmaxf(acc.y * dinv + bb.y, 0.f);
    val.z = fmaxf(acc.z * dinv + bb.z, 0.f);
    val.w = fmaxf(acc.w * dinv + bb.w, 0.f);
  }
  #pragma unroll
  for (int off = 8; off < 64; off <<= 1) {
    val.x += __shfl_xor(val.x, off, 64);
    val.y += __shfl_xor(val.y, off, 64);
    val.z += __shfl_xor(val.z, off, 64);
    val.w += __shfl_xor(val.w, off, 64);
  }
  __shared__ float red[4][32];
  int wid = tid >> 6, lane = tid & 63;
  if (lane < 8) {
    red[wid][lane * 4 + 0] = val.x;
    red[wid][lane * 4 + 1] = val.y;
    red[wid][lane * 4 + 2] = val.z;
    red[wid][lane * 4 + 3] = val.w;
  }
  __syncthreads();
  if (tid < 32) {
    float sum = red[0][tid] + red[1][tid] + red[2][tid] + red[3][tid];
    partials[((size_t)t * NBLK_G + gblk) * H_DIM + tid] = sum;
  }
}

// K5: reduce per-block partials -> pooled node-sum per (t,h)
__global__ void k_reduce(const float* __restrict__ partials, float* __restrict__ seq_raw,
                         int nblk) {
  int t = blockIdx.x;
  int tid = threadIdx.x;
  int h = tid & 31, w = tid >> 5;
  float sum = 0.f;
  for (int b = w; b < nblk; b += 8) sum += partials[((size_t)t * nblk + b) * H_DIM + h];
  __shared__ float red[8][32];
  red[w][h] = sum;
  __syncthreads();
  if (tid < 32) {
    float sm = 0.f;
    #pragma unroll
    for (int i = 0; i < 8; ++i) sm += red[i][tid];
    seq_raw[t * H_DIM + tid] = sm;
  }
}

// K6a: per-t x-part of LSTM gates
__global__ void k_gatex(const float* __restrict__ seq_raw, const float* __restrict__ w_ih,
                        const float* __restrict__ b_ih, const float* __restrict__ b_hh,
                        float* __restrict__ gx) {
  int t = blockIdx.x;
  int j = threadIdx.x;
  __shared__ float xb[32];
  if (j < 32) xb[j] = seq_raw[t * H_DIM + j] * (1.0f / (float)N_NODES);
  __syncthreads();
  float g = b_ih[j] + b_hh[j];
  #pragma unroll
  for (int k = 0; k < 32; ++k) g += w_ih[j * 32 + k] * xb[k];
  gx[t * 256 + j] = g;
}

// K6b: sequential LSTM (8 steps) + fc head.
__global__ void k_lstm(const float* __restrict__ gx, const float* __restrict__ w_hh,
                       const float* __restrict__ fc_w, const float* __restrict__ fc_b,
                       float* __restrict__ out) {
  __shared__ float hbuf[64], cbuf[64], gates[256];
  int j = threadIdx.x;
  if (j < 64) { hbuf[j] = 0.f; cbuf[j] = 0.f; }
  __syncthreads();
  for (int t = 0; t < T_DIM; ++t) {
    float g = gx[t * 256 + j];
    #pragma unroll 8
    for (int k = 0; k < 64; ++k) g += w_hh[j * 64 + k] * hbuf[k];
    gates[j] = g;
    __syncthreads();
    if (j < 64) {
      float ii = 1.f / (1.f + expf(-gates[j]));
      float ff = 1.f / (1.f + expf(-gates[64 + j]));
      float gg = tanhf(gates[128 + j]);
      float oo = 1.f / (1.f + expf(-gates[192 + j]));
      float c = ff * cbuf[j] + ii * gg;
      cbuf[j] = c;
      hbuf[j] = oo * tanhf(c);
    }
    __syncthreads();
  }
  if (j == 0) {
    float acc = 0.f;
    for (int k = 0; k < 64; ++k) acc += hbuf[k] * fc_w[k];
    out[0] = acc + fc_b[0];
  }
}

extern "C" void kernel_launch(void* const* d_in, const int* in_sizes, int n_in,
                              void* d_out, int out_size, void* d_ws, size_t ws_size,
                              hipStream_t stream) {
  const float* x      = (const float*)d_in[0];
  const int*   ei     = (const int*)  d_in[1];
  const float* conv_w = (const float*)d_in[2];
  const float* conv_b = (const float*)d_in[3];
  const float* w_ih   = (const float*)d_in[4];
  const float* w_hh   = (const float*)d_in[5];
  const float* b_ih   = (const float*)d_in[6];
  const float* b_hh   = (const float*)d_in[7];
  const float* fc_w   = (const float*)d_in[8];
  const float* fc_b   = (const float*)d_in[9];
  float* out = (float*)d_out;

  char* wsb = (char*)d_ws;
  size_t off = 0;
  auto alloc = [&](size_t bytes) {
    void* p = wsb + off;
    off = (off + bytes + 255) & ~(size_t)255;
    return p;
  };
  int* bincur   = (int*)alloc(sizeof(int) * T_DIM * NB);                    // 4 KB
  int* binbuf   = (int*)alloc(sizeof(int) * (size_t)T_DIM * NB * BIN_CAP);  // 32 MB
  int* deg      = (int*)alloc(sizeof(int) * T_DIM * N_NODES);               // 1.6 MB
  int* rowg     = (int*)alloc(sizeof(int) * (size_t)T_DIM * NB * (NPB + 1)); // 1.6 MB
  unsigned short* s = (unsigned short*)alloc(sizeof(unsigned short) * (size_t)T_DIM * N_NODES * H_DIM); // 25.6 MB
  float* partials = (float*)alloc(sizeof(float) * (size_t)T_DIM * NBLK_G * H_DIM);
  float* seq_raw  = (float*)alloc(sizeof(float) * T_DIM * H_DIM);
  float* gx       = (float*)alloc(sizeof(float) * T_DIM * 256);

  (void)hipMemsetAsync(bincur, 0, sizeof(int) * T_DIM * NB, stream);

  dim3 gA(E_EDGES / CHUNK_A, T_DIM);      // 50 x 8
  k_part<<<gA, 256, 0, stream>>>(ei, bincur, binbuf);
  k_degfill<<<T_DIM * NB, 256, 0, stream>>>(bincur, binbuf, deg, rowg);
  dim3 g4((N_NODES + 255) / 256, T_DIM);
  k_xw<<<g4, 256, 0, stream>>>(x, conv_w, deg, s);
  k_gather2<<<NBLK_G * T_DIM, 256, 0, stream>>>(s, binbuf, rowg, conv_b, partials);
  k_reduce<<<T_DIM, 256, 0, stream>>>(partials, seq_raw, NBLK_G);
  k_gatex<<<T_DIM, 256, 0, stream>>>(seq_raw, w_ih, b_ih, b_hh, gx);
  k_lstm<<<1, 256, 0, stream>>>(gx, w_hh, fc_w, fc_b, out);
}

// Round 6
// 320.297 us; speedup vs baseline: 4.6154x; 1.0920x over previous
//
#include <hip/hip_runtime.h>
#include <hip/hip_bf16.h>
#include <cstdint>
#include <cstddef>

#define T_DIM 8
#define N_NODES 50000
#define F_DIM 64
#define H_DIM 32
#define L_DIM 64
#define E_EDGES 800000

#define NB 128            // dst bins per t
#define NPB 391           // nodes per bin (128*391 = 50048 >= 50000)
#define BIN_CAP 8192      // mean 6250 + 24 sigma
#define CHUNK_A 16000     // edges per k_part block (50 blocks per t)
#define NBLK_G 1563       // ceil(N_NODES/32) node-groups per t

__device__ __forceinline__ unsigned short f2bf(float f) {
  unsigned u = __float_as_uint(f);
  u = u + 0x7FFFu + ((u >> 16) & 1u);   // round-to-nearest-even
  return (unsigned short)(u >> 16);
}
__device__ __forceinline__ float bf2f(unsigned short b) {
  return __uint_as_float(((unsigned)b) << 16);
}

// K1: radix-partition edges into 128 dst-bins per t, packed (dl<<16)|src.
__global__ void k_part(const int* __restrict__ ei, int* __restrict__ bincur,
                       int* __restrict__ binbuf) {
  int t = blockIdx.y;
  int e0 = blockIdx.x * CHUNK_A;
  const int* dstp = ei + (size_t)(t * 2 + 1) * E_EDGES;
  const int* srcp = ei + (size_t)(t * 2 + 0) * E_EDGES;
  __shared__ int hist[NB], bbase[NB];
  int tid = threadIdx.x;
  for (int i = tid; i < NB; i += 256) hist[i] = 0;
  __syncthreads();
  const int4* d4 = reinterpret_cast<const int4*>(dstp + e0);
  const int4* s4 = reinterpret_cast<const int4*>(srcp + e0);
  for (int q = tid; q < CHUNK_A / 4; q += 256) {
    int4 d = d4[q];
    #pragma unroll
    for (int k = 0; k < 4; ++k) {
      int dst = (k == 0) ? d.x : (k == 1) ? d.y : (k == 2) ? d.z : d.w;
      atomicAdd(&hist[dst / NPB], 1);
    }
  }
  __syncthreads();
  for (int i = tid; i < NB; i += 256) {
    int c = hist[i];
    bbase[i] = atomicAdd(&bincur[t * NB + i], c);
    hist[i] = 0;
  }
  __syncthreads();
  for (int q = tid; q < CHUNK_A / 4; q += 256) {
    int4 d = d4[q];     // L2-hot re-read
    int4 s = s4[q];
    #pragma unroll
    for (int k = 0; k < 4; ++k) {
      int dst = (k == 0) ? d.x : (k == 1) ? d.y : (k == 2) ? d.z : d.w;
      int src = (k == 0) ? s.x : (k == 1) ? s.y : (k == 2) ? s.z : s.w;
      int b = dst / NPB;
      int dl = dst - b * NPB;
      int off = bbase[b] + atomicAdd(&hist[b], 1);
      if (off < BIN_CAP)
        binbuf[(size_t)(t * NB + b) * BIN_CAP + off] = (dl << 16) | src;
    }
  }
}

// K2: per-(t,bin) finalize: LDS stage -> per-node histogram (deg) -> block
// scan (rowg) -> in-place counting sort by local node.
__global__ void k_degfill(const int* __restrict__ bincur, int* __restrict__ binbuf,
                          int* __restrict__ deg, int* __restrict__ rowg) {
  int b = blockIdx.x & (NB - 1);
  int t = blockIdx.x >> 7;
  __shared__ int stage[BIN_CAP];        // 32KB
  __shared__ int hist[NPB], rowoff[NPB + 1];
  __shared__ int wsum[4];
  int tid = threadIdx.x;
  int cnt = bincur[t * NB + b];
  if (cnt > BIN_CAP) cnt = BIN_CAP;
  int* gbuf = binbuf + (size_t)(t * NB + b) * BIN_CAP;
  for (int i = tid; i < cnt; i += 256) stage[i] = gbuf[i];
  for (int i = tid; i < NPB; i += 256) hist[i] = 0;
  __syncthreads();
  for (int i = tid; i < cnt; i += 256) atomicAdd(&hist[stage[i] >> 16], 1);
  __syncthreads();
  int nb0 = b * NPB;
  for (int dl = tid; dl < NPB; dl += 256) {
    int n = nb0 + dl;
    if (n < N_NODES) deg[t * N_NODES + n] = hist[dl];
  }
  // block exclusive scan of hist[0..NPB)
  int i0 = 2 * tid, i1 = 2 * tid + 1;
  int a0 = (i0 < NPB) ? hist[i0] : 0;
  int a1 = (i1 < NPB) ? hist[i1] : 0;
  int tsum = a0 + a1;
  int lane = tid & 63, wid = tid >> 6;
  int sc = tsum;
  #pragma unroll
  for (int off = 1; off < 64; off <<= 1) {
    int o = __shfl_up(sc, off, 64);
    if (lane >= off) sc += o;
  }
  if (lane == 63) wsum[wid] = sc;
  __syncthreads();
  if (tid == 0) {
    int c = 0;
    for (int k = 0; k < 4; ++k) { int v = wsum[k]; wsum[k] = c; c += v; }
  }
  __syncthreads();
  int excl = wsum[wid] + (sc - tsum);
  if (i0 < NPB) rowoff[i0] = excl;
  if (i1 < NPB) rowoff[i1] = excl + a0;
  if (tid == 0) rowoff[NPB] = cnt;
  __syncthreads();
  int* rg = rowg + (size_t)(t * NB + b) * (NPB + 1);
  for (int i = tid; i <= NPB; i += 256) rg[i] = rowoff[i];
  for (int i = tid; i < NPB; i += 256) hist[i] = 0;   // reuse as cursor
  __syncthreads();
  for (int i = tid; i < cnt; i += 256) {
    int w = stage[i];
    int dl = w >> 16;
    int pos = rowoff[dl] + atomicAdd(&hist[dl], 1);
    gbuf[pos] = w & 0xFFFF;           // src only, sorted by local node
  }
}

// K3: s = rsqrt(deg+1) * (x @ conv_w), bf16. Block stages 256 x-rows (64KB)
// in LDS with fully-coalesced global loads (fixes 3.5x HBM over-fetch from
// 256B-strided per-thread row loads); slot-XOR swizzle caps LDS read
// conflicts at 4-way. w read via wave-uniform scalar loads.
__global__ void k_xw(const float* __restrict__ x, const float* __restrict__ w,
                     const int* __restrict__ deg, unsigned short* __restrict__ s) {
  int t = blockIdx.y;
  int bn0 = blockIdx.x * 256;
  int tid = threadIdx.x;
  __shared__ float4 xs[256 * 16];       // 64KB
  const float4* gx = reinterpret_cast<const float4*>(x + ((size_t)t * N_NODES + bn0) * F_DIM);
  int nrem = N_NODES - bn0;             // may be < 256 in last block
  #pragma unroll
  for (int i = 0; i < 16; ++i) {
    int q = tid + i * 256;
    int node = q >> 4, k4 = q & 15;
    if (node < nrem) xs[node * 16 + (k4 ^ (node & 15))] = gx[q];
  }
  __syncthreads();
  int n = bn0 + tid;
  if (n >= N_NODES) return;
  const float4* w4 = reinterpret_cast<const float4*>(w);
  float4 acc[8];
  #pragma unroll
  for (int h = 0; h < 8; ++h) acc[h] = make_float4(0.f, 0.f, 0.f, 0.f);
  #pragma unroll
  for (int k4 = 0; k4 < 16; ++k4) {
    float4 xv = xs[tid * 16 + (k4 ^ (tid & 15))];
    #pragma unroll
    for (int kk = 0; kk < 4; ++kk) {
      float xsc = (kk == 0) ? xv.x : (kk == 1) ? xv.y : (kk == 2) ? xv.z : xv.w;
      #pragma unroll
      for (int h = 0; h < 8; ++h) {
        float4 wv = w4[(k4 * 4 + kk) * 8 + h];   // wave-uniform -> scalar loads
        acc[h].x += xsc * wv.x; acc[h].y += xsc * wv.y;
        acc[h].z += xsc * wv.z; acc[h].w += xsc * wv.w;
      }
    }
  }
  float dinv = rsqrtf((float)(deg[t * N_NODES + n] + 1));
  unsigned short* srow = s + ((size_t)t * N_NODES + n) * H_DIM;
  #pragma unroll
  for (int h = 0; h < 8; ++h) {
    uint2 u;
    u.x = (unsigned)f2bf(acc[h].x * dinv) | ((unsigned)f2bf(acc[h].y * dinv) << 16);
    u.y = (unsigned)f2bf(acc[h].z * dinv) | ((unsigned)f2bf(acc[h].w * dinv) << 16);
    *reinterpret_cast<uint2*>(srow + h * 4) = u;
  }
}

// K4: atomic-free per-node gather via rowg. t = bid&7 pins each t to one XCD.
__global__ void k_gather2(const unsigned short* __restrict__ s, const int* __restrict__ binsrt,
                          const int* __restrict__ rowg, const float* __restrict__ conv_b,
                          float* __restrict__ partials) {
  int bid = blockIdx.x;
  int t = bid & 7;
  int gblk = bid >> 3;                  // 0..NBLK_G-1
  int tid = threadIdx.x;
  int g = tid >> 3, j = tid & 7;        // 32 nodes x 8 feature-lanes
  int n = gblk * 32 + g;
  float4 val = make_float4(0.f, 0.f, 0.f, 0.f);
  if (n < N_NODES) {
    int b = n / NPB, dl = n - b * NPB;
    const int* ro = rowg + (size_t)(t * NB + b) * (NPB + 1);
    int start = ro[dl], end = ro[dl + 1];
    float dinv = rsqrtf((float)(end - start + 1));
    const unsigned short* sbase = s + (size_t)t * N_NODES * H_DIM;
    ushort4 u = *reinterpret_cast<const ushort4*>(sbase + (size_t)n * H_DIM + j * 4);
    float4 acc = make_float4(bf2f(u.x), bf2f(u.y), bf2f(u.z), bf2f(u.w));
    const int* col = binsrt + (size_t)(t * NB + b) * BIN_CAP;
    for (int p = start; p < end; ++p) {
      int c = col[p];                   // broadcast across the 8 lanes
      ushort4 v = *reinterpret_cast<const ushort4*>(sbase + (size_t)c * H_DIM + j * 4);
      acc.x += bf2f(v.x); acc.y += bf2f(v.y); acc.z += bf2f(v.z); acc.w += bf2f(v.w);
    }
    const float4 bb = reinterpret_cast<const float4*>(conv_b)[j];
    val.x = fmaxf(acc.x * dinv + bb.x, 0.f);
    val.y = fmaxf(acc.y * dinv + bb.y, 0.f);
    val.z = fmaxf(acc.z * dinv + bb.z, 0.f);
    val.w = fmaxf(acc.w * dinv + bb.w, 0.f);
  }
  #pragma unroll
  for (int off = 8; off < 64; off <<= 1) {
    val.x += __shfl_xor(val.x, off, 64);
    val.y += __shfl_xor(val.y, off, 64);
    val.z += __shfl_xor(val.z, off, 64);
    val.w += __shfl_xor(val.w, off, 64);
  }
  __shared__ float red[4][32];
  int wid = tid >> 6, lane = tid & 63;
  if (lane < 8) {
    red[wid][lane * 4 + 0] = val.x;
    red[wid][lane * 4 + 1] = val.y;
    red[wid][lane * 4 + 2] = val.z;
    red[wid][lane * 4 + 3] = val.w;
  }
  __syncthreads();
  if (tid < 32) {
    float sum = red[0][tid] + red[1][tid] + red[2][tid] + red[3][tid];
    partials[((size_t)t * NBLK_G + gblk) * H_DIM + tid] = sum;
  }
}

// K5: reduce per-block partials -> pooled node-sum per (t,h)
__global__ void k_reduce(const float* __restrict__ partials, float* __restrict__ seq_raw,
                         int nblk) {
  int t = blockIdx.x;
  int tid = threadIdx.x;
  int h = tid & 31, w = tid >> 5;
  float sum = 0.f;
  for (int b = w; b < nblk; b += 8) sum += partials[((size_t)t * nblk + b) * H_DIM + h];
  __shared__ float red[8][32];
  red[w][h] = sum;
  __syncthreads();
  if (tid < 32) {
    float sm = 0.f;
    #pragma unroll
    for (int i = 0; i < 8; ++i) sm += red[i][tid];
    seq_raw[t * H_DIM + tid] = sm;
  }
}

// K6a: per-t x-part of LSTM gates
__global__ void k_gatex(const float* __restrict__ seq_raw, const float* __restrict__ w_ih,
                        const float* __restrict__ b_ih, const float* __restrict__ b_hh,
                        float* __restrict__ gx) {
  int t = blockIdx.x;
  int j = threadIdx.x;
  __shared__ float xb[32];
  if (j < 32) xb[j] = seq_raw[t * H_DIM + j] * (1.0f / (float)N_NODES);
  __syncthreads();
  float g = b_ih[j] + b_hh[j];
  #pragma unroll
  for (int k = 0; k < 32; ++k) g += w_ih[j * 32 + k] * xb[k];
  gx[t * 256 + j] = g;
}

// K6b: sequential LSTM (8 steps) + fc head.
__global__ void k_lstm(const float* __restrict__ gx, const float* __restrict__ w_hh,
                       const float* __restrict__ fc_w, const float* __restrict__ fc_b,
                       float* __restrict__ out) {
  __shared__ float hbuf[64], cbuf[64], gates[256];
  int j = threadIdx.x;
  if (j < 64) { hbuf[j] = 0.f; cbuf[j] = 0.f; }
  __syncthreads();
  for (int t = 0; t < T_DIM; ++t) {
    float g = gx[t * 256 + j];
    #pragma unroll 8
    for (int k = 0; k < 64; ++k) g += w_hh[j * 64 + k] * hbuf[k];
    gates[j] = g;
    __syncthreads();
    if (j < 64) {
      float ii = 1.f / (1.f + expf(-gates[j]));
      float ff = 1.f / (1.f + expf(-gates[64 + j]));
      float gg = tanhf(gates[128 + j]);
      float oo = 1.f / (1.f + expf(-gates[192 + j]));
      float c = ff * cbuf[j] + ii * gg;
      cbuf[j] = c;
      hbuf[j] = oo * tanhf(c);
    }
    __syncthreads();
  }
  if (j == 0) {
    float acc = 0.f;
    for (int k = 0; k < 64; ++k) acc += hbuf[k] * fc_w[k];
    out[0] = acc + fc_b[0];
  }
}

extern "C" void kernel_launch(void* const* d_in, const int* in_sizes, int n_in,
                              void* d_out, int out_size, void* d_ws, size_t ws_size,
                              hipStream_t stream) {
  const float* x      = (const float*)d_in[0];
  const int*   ei     = (const int*)  d_in[1];
  const float* conv_w = (const float*)d_in[2];
  const float* conv_b = (const float*)d_in[3];
  const float* w_ih   = (const float*)d_in[4];
  const float* w_hh   = (const float*)d_in[5];
  const float* b_ih   = (const float*)d_in[6];
  const float* b_hh   = (const float*)d_in[7];
  const float* fc_w   = (const float*)d_in[8];
  const float* fc_b   = (const float*)d_in[9];
  float* out = (float*)d_out;

  char* wsb = (char*)d_ws;
  size_t off = 0;
  auto alloc = [&](size_t bytes) {
    void* p = wsb + off;
    off = (off + bytes + 255) & ~(size_t)255;
    return p;
  };
  int* bincur   = (int*)alloc(sizeof(int) * T_DIM * NB);                    // 4 KB
  int* binbuf   = (int*)alloc(sizeof(int) * (size_t)T_DIM * NB * BIN_CAP);  // 32 MB
  int* deg      = (int*)alloc(sizeof(int) * T_DIM * N_NODES);               // 1.6 MB
  int* rowg     = (int*)alloc(sizeof(int) * (size_t)T_DIM * NB * (NPB + 1)); // 1.6 MB
  unsigned short* s = (unsigned short*)alloc(sizeof(unsigned short) * (size_t)T_DIM * N_NODES * H_DIM); // 25.6 MB
  float* partials = (float*)alloc(sizeof(float) * (size_t)T_DIM * NBLK_G * H_DIM);
  float* seq_raw  = (float*)alloc(sizeof(float) * T_DIM * H_DIM);
  float* gx       = (float*)alloc(sizeof(float) * T_DIM * 256);

  (void)hipMemsetAsync(bincur, 0, sizeof(int) * T_DIM * NB, stream);

  dim3 gA(E_EDGES / CHUNK_A, T_DIM);      // 50 x 8
  k_part<<<gA, 256, 0, stream>>>(ei, bincur, binbuf);
  k_degfill<<<T_DIM * NB, 256, 0, stream>>>(bincur, binbuf, deg, rowg);
  dim3 g4((N_NODES + 255) / 256, T_DIM);
  k_xw<<<g4, 256, 0, stream>>>(x, conv_w, deg, s);
  k_gather2<<<NBLK_G * T_DIM, 256, 0, stream>>>(s, binbuf, rowg, conv_b, partials);
  k_reduce<<<T_DIM, 256, 0, stream>>>(partials, seq_raw, NBLK_G);
  k_gatex<<<T_DIM, 256, 0, stream>>>(seq_raw, w_ih, b_ih, b_hh, gx);
  k_lstm<<<1, 256, 0, stream>>>(gx, w_hh, fc_w, fc_b, out);
}

// Round 7
// 280.373 us; speedup vs baseline: 5.2726x; 1.1424x over previous
//
#include <hip/hip_runtime.h>
#include <hip/hip_bf16.h>
#include <cstdint>
#include <cstddef>

#define T_DIM 8
#define N_NODES 50000
#define F_DIM 64
#define H_DIM 32
#define L_DIM 64
#define E_EDGES 800000

#define NB 128            // dst bins per t
#define NPB 391           // nodes per bin (128*391 = 50048 >= 50000)
#define BIN_CAP 8192      // mean 6250 + 24 sigma
#define CHUNK_A 16000     // edges per k_part block (50 blocks per t)
#define NBLK_G 1563       // ceil(N_NODES/32) node-groups per t

__device__ __forceinline__ unsigned short f2bf(float f) {
  unsigned u = __float_as_uint(f);
  u = u + 0x7FFFu + ((u >> 16) & 1u);   // round-to-nearest-even
  return (unsigned short)(u >> 16);
}
__device__ __forceinline__ float bf2f(unsigned short b) {
  return __uint_as_float(((unsigned)b) << 16);
}

// K1: radix-partition edges into 128 dst-bins per t, packed (dl<<16)|src.
__global__ void k_part(const int* __restrict__ ei, int* __restrict__ bincur,
                       int* __restrict__ binbuf) {
  int t = blockIdx.y;
  int e0 = blockIdx.x * CHUNK_A;
  const int* dstp = ei + (size_t)(t * 2 + 1) * E_EDGES;
  const int* srcp = ei + (size_t)(t * 2 + 0) * E_EDGES;
  __shared__ int hist[NB], bbase[NB];
  int tid = threadIdx.x;
  for (int i = tid; i < NB; i += 256) hist[i] = 0;
  __syncthreads();
  const int4* d4 = reinterpret_cast<const int4*>(dstp + e0);
  const int4* s4 = reinterpret_cast<const int4*>(srcp + e0);
  for (int q = tid; q < CHUNK_A / 4; q += 256) {
    int4 d = d4[q];
    #pragma unroll
    for (int k = 0; k < 4; ++k) {
      int dst = (k == 0) ? d.x : (k == 1) ? d.y : (k == 2) ? d.z : d.w;
      atomicAdd(&hist[dst / NPB], 1);
    }
  }
  __syncthreads();
  for (int i = tid; i < NB; i += 256) {
    int c = hist[i];
    bbase[i] = atomicAdd(&bincur[t * NB + i], c);
    hist[i] = 0;
  }
  __syncthreads();
  for (int q = tid; q < CHUNK_A / 4; q += 256) {
    int4 d = d4[q];     // L2-hot re-read
    int4 s = s4[q];
    #pragma unroll
    for (int k = 0; k < 4; ++k) {
      int dst = (k == 0) ? d.x : (k == 1) ? d.y : (k == 2) ? d.z : d.w;
      int src = (k == 0) ? s.x : (k == 1) ? s.y : (k == 2) ? s.z : s.w;
      int b = dst / NPB;
      int dl = dst - b * NPB;
      int off = bbase[b] + atomicAdd(&hist[b], 1);
      if (off < BIN_CAP)
        binbuf[(size_t)(t * NB + b) * BIN_CAP + off] = (dl << 16) | src;
    }
  }
}

// K2: per-(t,bin) finalize: LDS stage -> per-node histogram (deg) -> block
// scan (rowg) -> in-place counting sort by local node.
__global__ void k_degfill(const int* __restrict__ bincur, int* __restrict__ binbuf,
                          int* __restrict__ deg, int* __restrict__ rowg) {
  int b = blockIdx.x & (NB - 1);
  int t = blockIdx.x >> 7;
  __shared__ int stage[BIN_CAP];        // 32KB
  __shared__ int hist[NPB], rowoff[NPB + 1];
  __shared__ int wsum[4];
  int tid = threadIdx.x;
  int cnt = bincur[t * NB + b];
  if (cnt > BIN_CAP) cnt = BIN_CAP;
  int* gbuf = binbuf + (size_t)(t * NB + b) * BIN_CAP;
  for (int i = tid; i < cnt; i += 256) stage[i] = gbuf[i];
  for (int i = tid; i < NPB; i += 256) hist[i] = 0;
  __syncthreads();
  for (int i = tid; i < cnt; i += 256) atomicAdd(&hist[stage[i] >> 16], 1);
  __syncthreads();
  int nb0 = b * NPB;
  for (int dl = tid; dl < NPB; dl += 256) {
    int n = nb0 + dl;
    if (n < N_NODES) deg[t * N_NODES + n] = hist[dl];
  }
  // block exclusive scan of hist[0..NPB)
  int i0 = 2 * tid, i1 = 2 * tid + 1;
  int a0 = (i0 < NPB) ? hist[i0] : 0;
  int a1 = (i1 < NPB) ? hist[i1] : 0;
  int tsum = a0 + a1;
  int lane = tid & 63, wid = tid >> 6;
  int sc = tsum;
  #pragma unroll
  for (int off = 1; off < 64; off <<= 1) {
    int o = __shfl_up(sc, off, 64);
    if (lane >= off) sc += o;
  }
  if (lane == 63) wsum[wid] = sc;
  __syncthreads();
  if (tid == 0) {
    int c = 0;
    for (int k = 0; k < 4; ++k) { int v = wsum[k]; wsum[k] = c; c += v; }
  }
  __syncthreads();
  int excl = wsum[wid] + (sc - tsum);
  if (i0 < NPB) rowoff[i0] = excl;
  if (i1 < NPB) rowoff[i1] = excl + a0;
  if (tid == 0) rowoff[NPB] = cnt;
  __syncthreads();
  int* rg = rowg + (size_t)(t * NB + b) * (NPB + 1);
  for (int i = tid; i <= NPB; i += 256) rg[i] = rowoff[i];
  for (int i = tid; i < NPB; i += 256) hist[i] = 0;   // reuse as cursor
  __syncthreads();
  for (int i = tid; i < cnt; i += 256) {
    int w = stage[i];
    int dl = w >> 16;
    int pos = rowoff[dl] + atomicAdd(&hist[dl], 1);
    gbuf[pos] = w & 0xFFFF;           // src only, sorted by local node
  }
}

// K3: s = rsqrt(deg+1) * (x @ conv_w), bf16. 128-node tile (32KB f32 LDS ->
// 5 blocks/CU, fixes R6's 20% occupancy), 2 threads per node each doing a
// 32-k half (k-half = tid>>7, wave-uniform -> readfirstlane keeps conv_w on
// the scalar path). Halves combined through the same LDS buffer.
__global__ void k_xw(const float* __restrict__ x, const float* __restrict__ w,
                     const int* __restrict__ deg, unsigned short* __restrict__ s) {
  int t = blockIdx.y;
  int bn0 = blockIdx.x * 128;
  int tid = threadIdx.x;
  __shared__ float4 xs4[128 * 16];      // 32KB: x rows, slot-swizzled
  const float4* gx4 = reinterpret_cast<const float4*>(x + ((size_t)t * N_NODES + bn0) * F_DIM);
  int nrem = N_NODES - bn0;             // may be < 128 in last block
  #pragma unroll
  for (int i = 0; i < 8; ++i) {
    int q = tid + i * 256;              // 0..2047
    int node = q >> 4, c = q & 15;
    if (node < nrem) xs4[node * 16 + (c ^ (node & 15))] = gx4[q];
  }
  __syncthreads();
  int node = tid & 127;
  int kh = __builtin_amdgcn_readfirstlane(tid >> 7);  // wave-uniform k-half
  int n = bn0 + node;
  bool act = (node < nrem);
  const float4* w4 = reinterpret_cast<const float4*>(w);
  float4 acc[8];
  #pragma unroll
  for (int h = 0; h < 8; ++h) acc[h] = make_float4(0.f, 0.f, 0.f, 0.f);
  if (act) {
    #pragma unroll
    for (int cc = 0; cc < 8; ++cc) {
      int c = kh * 8 + cc;
      float4 xv = xs4[node * 16 + (c ^ (node & 15))];
      #pragma unroll
      for (int kk = 0; kk < 4; ++kk) {
        float xsc = (kk == 0) ? xv.x : (kk == 1) ? xv.y : (kk == 2) ? xv.z : xv.w;
        int k = c * 4 + kk;
        #pragma unroll
        for (int h = 0; h < 8; ++h) {
          float4 wv = w4[k * 8 + h];    // k wave-uniform -> s_load
          acc[h].x += xsc * wv.x; acc[h].y += xsc * wv.y;
          acc[h].z += xsc * wv.z; acc[h].w += xsc * wv.w;
        }
      }
    }
  }
  __syncthreads();                      // all xs reads done; reuse buffer
  float4* pb = xs4;                     // partial sums: [128 nodes][8 h-quads]
  if (kh == 0 && act) {
    #pragma unroll
    for (int h = 0; h < 8; ++h) pb[node * 8 + (h ^ (node & 7))] = acc[h];
  }
  __syncthreads();
  if (kh == 1 && act) {
    float dinv = rsqrtf((float)(deg[t * N_NODES + n] + 1));
    unsigned short* srow = s + ((size_t)t * N_NODES + n) * H_DIM;
    #pragma unroll
    for (int h = 0; h < 8; h += 2) {
      float4 p0 = pb[node * 8 + (h ^ (node & 7))];
      float4 p1 = pb[node * 8 + ((h + 1) ^ (node & 7))];
      float4 a0 = acc[h], a1 = acc[h + 1];
      a0.x += p0.x; a0.y += p0.y; a0.z += p0.z; a0.w += p0.w;
      a1.x += p1.x; a1.y += p1.y; a1.z += p1.z; a1.w += p1.w;
      uint4 u;
      u.x = (unsigned)f2bf(a0.x * dinv) | ((unsigned)f2bf(a0.y * dinv) << 16);
      u.y = (unsigned)f2bf(a0.z * dinv) | ((unsigned)f2bf(a0.w * dinv) << 16);
      u.z = (unsigned)f2bf(a1.x * dinv) | ((unsigned)f2bf(a1.y * dinv) << 16);
      u.w = (unsigned)f2bf(a1.z * dinv) | ((unsigned)f2bf(a1.w * dinv) << 16);
      *reinterpret_cast<uint4*>(srow + h * 4) = u;
    }
  }
}

// K4: atomic-free per-node gather via rowg. t = bid&7 pins each t to one XCD.
__global__ void k_gather2(const unsigned short* __restrict__ s, const int* __restrict__ binsrt,
                          const int* __restrict__ rowg, const float* __restrict__ conv_b,
                          float* __restrict__ partials) {
  int bid = blockIdx.x;
  int t = bid & 7;
  int gblk = bid >> 3;                  // 0..NBLK_G-1
  int tid = threadIdx.x;
  int g = tid >> 3, j = tid & 7;        // 32 nodes x 8 feature-lanes
  int n = gblk * 32 + g;
  float4 val = make_float4(0.f, 0.f, 0.f, 0.f);
  if (n < N_NODES) {
    int b = n / NPB, dl = n - b * NPB;
    const int* ro = rowg + (size_t)(t * NB + b) * (NPB + 1);
    int start = ro[dl], end = ro[dl + 1];
    float dinv = rsqrtf((float)(end - start + 1));
    const unsigned short* sbase = s + (size_t)t * N_NODES * H_DIM;
    ushort4 u = *reinterpret_cast<const ushort4*>(sbase + (size_t)n * H_DIM + j * 4);
    float4 acc = make_float4(bf2f(u.x), bf2f(u.y), bf2f(u.z), bf2f(u.w));
    const int* col = binsrt + (size_t)(t * NB + b) * BIN_CAP;
    for (int p = start; p < end; ++p) {
      int c = col[p];                   // broadcast across the 8 lanes
      ushort4 v = *reinterpret_cast<const ushort4*>(sbase + (size_t)c * H_DIM + j * 4);
      acc.x += bf2f(v.x); acc.y += bf2f(v.y); acc.z += bf2f(v.z); acc.w += bf2f(v.w);
    }
    const float4 bb = reinterpret_cast<const float4*>(conv_b)[j];
    val.x = fmaxf(acc.x * dinv + bb.x, 0.f);
    val.y = fmaxf(acc.y * dinv + bb.y, 0.f);
    val.z = fmaxf(acc.z * dinv + bb.z, 0.f);
    val.w = fmaxf(acc.w * dinv + bb.w, 0.f);
  }
  #pragma unroll
  for (int off = 8; off < 64; off <<= 1) {
    val.x += __shfl_xor(val.x, off, 64);
    val.y += __shfl_xor(val.y, off, 64);
    val.z += __shfl_xor(val.z, off, 64);
    val.w += __shfl_xor(val.w, off, 64);
  }
  __shared__ float red[4][32];
  int wid = tid >> 6, lane = tid & 63;
  if (lane < 8) {
    red[wid][lane * 4 + 0] = val.x;
    red[wid][lane * 4 + 1] = val.y;
    red[wid][lane * 4 + 2] = val.z;
    red[wid][lane * 4 + 3] = val.w;
  }
  __syncthreads();
  if (tid < 32) {
    float sum = red[0][tid] + red[1][tid] + red[2][tid] + red[3][tid];
    partials[((size_t)t * NBLK_G + gblk) * H_DIM + tid] = sum;
  }
}

// K5: reduce per-block partials -> pooled node-sum per (t,h)
__global__ void k_reduce(const float* __restrict__ partials, float* __restrict__ seq_raw,
                         int nblk) {
  int t = blockIdx.x;
  int tid = threadIdx.x;
  int h = tid & 31, w = tid >> 5;
  float sum = 0.f;
  for (int b = w; b < nblk; b += 8) sum += partials[((size_t)t * nblk + b) * H_DIM + h];
  __shared__ float red[8][32];
  red[w][h] = sum;
  __syncthreads();
  if (tid < 32) {
    float sm = 0.f;
    #pragma unroll
    for (int i = 0; i < 8; ++i) sm += red[i][tid];
    seq_raw[t * H_DIM + tid] = sm;
  }
}

// K6a: per-t x-part of LSTM gates
__global__ void k_gatex(const float* __restrict__ seq_raw, const float* __restrict__ w_ih,
                        const float* __restrict__ b_ih, const float* __restrict__ b_hh,
                        float* __restrict__ gx) {
  int t = blockIdx.x;
  int j = threadIdx.x;
  __shared__ float xb[32];
  if (j < 32) xb[j] = seq_raw[t * H_DIM + j] * (1.0f / (float)N_NODES);
  __syncthreads();
  float g = b_ih[j] + b_hh[j];
  #pragma unroll
  for (int k = 0; k < 32; ++k) g += w_ih[j * 32 + k] * xb[k];
  gx[t * 256 + j] = g;
}

// K6b: sequential LSTM (8 steps) + fc head.
__global__ void k_lstm(const float* __restrict__ gx, const float* __restrict__ w_hh,
                       const float* __restrict__ fc_w, const float* __restrict__ fc_b,
                       float* __restrict__ out) {
  __shared__ float hbuf[64], cbuf[64], gates[256];
  int j = threadIdx.x;
  if (j < 64) { hbuf[j] = 0.f; cbuf[j] = 0.f; }
  __syncthreads();
  for (int t = 0; t < T_DIM; ++t) {
    float g = gx[t * 256 + j];
    #pragma unroll 8
    for (int k = 0; k < 64; ++k) g += w_hh[j * 64 + k] * hbuf[k];
    gates[j] = g;
    __syncthreads();
    if (j < 64) {
      float ii = 1.f / (1.f + expf(-gates[j]));
      float ff = 1.f / (1.f + expf(-gates[64 + j]));
      float gg = tanhf(gates[128 + j]);
      float oo = 1.f / (1.f + expf(-gates[192 + j]));
      float c = ff * cbuf[j] + ii * gg;
      cbuf[j] = c;
      hbuf[j] = oo * tanhf(c);
    }
    __syncthreads();
  }
  if (j == 0) {
    float acc = 0.f;
    for (int k = 0; k < 64; ++k) acc += hbuf[k] * fc_w[k];
    out[0] = acc + fc_b[0];
  }
}

extern "C" void kernel_launch(void* const* d_in, const int* in_sizes, int n_in,
                              void* d_out, int out_size, void* d_ws, size_t ws_size,
                              hipStream_t stream) {
  const float* x      = (const float*)d_in[0];
  const int*   ei     = (const int*)  d_in[1];
  const float* conv_w = (const float*)d_in[2];
  const float* conv_b = (const float*)d_in[3];
  const float* w_ih   = (const float*)d_in[4];
  const float* w_hh   = (const float*)d_in[5];
  const float* b_ih   = (const float*)d_in[6];
  const float* b_hh   = (const float*)d_in[7];
  const float* fc_w   = (const float*)d_in[8];
  const float* fc_b   = (const float*)d_in[9];
  float* out = (float*)d_out;

  char* wsb = (char*)d_ws;
  size_t off = 0;
  auto alloc = [&](size_t bytes) {
    void* p = wsb + off;
    off = (off + bytes + 255) & ~(size_t)255;
    return p;
  };
  int* bincur   = (int*)alloc(sizeof(int) * T_DIM * NB);                    // 4 KB
  int* binbuf   = (int*)alloc(sizeof(int) * (size_t)T_DIM * NB * BIN_CAP);  // 32 MB
  int* deg      = (int*)alloc(sizeof(int) * T_DIM * N_NODES);               // 1.6 MB
  int* rowg     = (int*)alloc(sizeof(int) * (size_t)T_DIM * NB * (NPB + 1)); // 1.6 MB
  unsigned short* s = (unsigned short*)alloc(sizeof(unsigned short) * (size_t)T_DIM * N_NODES * H_DIM); // 25.6 MB
  float* partials = (float*)alloc(sizeof(float) * (size_t)T_DIM * NBLK_G * H_DIM);
  float* seq_raw  = (float*)alloc(sizeof(float) * T_DIM * H_DIM);
  float* gx       = (float*)alloc(sizeof(float) * T_DIM * 256);

  (void)hipMemsetAsync(bincur, 0, sizeof(int) * T_DIM * NB, stream);

  dim3 gA(E_EDGES / CHUNK_A, T_DIM);      // 50 x 8
  k_part<<<gA, 256, 0, stream>>>(ei, bincur, binbuf);
  k_degfill<<<T_DIM * NB, 256, 0, stream>>>(bincur, binbuf, deg, rowg);
  dim3 g4((N_NODES + 127) / 128, T_DIM);  // 391 x 8
  k_xw<<<g4, 256, 0, stream>>>(x, conv_w, deg, s);
  k_gather2<<<NBLK_G * T_DIM, 256, 0, stream>>>(s, binbuf, rowg, conv_b, partials);
  k_reduce<<<T_DIM, 256, 0, stream>>>(partials, seq_raw, NBLK_G);
  k_gatex<<<T_DIM, 256, 0, stream>>>(seq_raw, w_ih, b_ih, b_hh, gx);
  k_lstm<<<1, 256, 0, stream>>>(gx, w_hh, fc_w, fc_b, out);
}

// Round 8
// 236.970 us; speedup vs baseline: 6.2383x; 1.1832x over previous
//
#include <hip/hip_runtime.h>
#include <hip/hip_bf16.h>
#include <cstdint>
#include <cstddef>

#define T_DIM 8
#define N_NODES 50000
#define F_DIM 64
#define H_DIM 32
#define L_DIM 64
#define E_EDGES 800000

#define NB 128            // dst bins per t
#define NPB 391           // nodes per bin (128*391 = 50048 >= 50000)
#define BIN_CAP 8192      // mean 6250 + 24 sigma
#define CHUNK_A 16000     // edges per k_part block (50 blocks per t)
#define NBLK_G2 782       // ceil(N_NODES/64) node-groups per t

__device__ __forceinline__ unsigned short f2bf(float f) {
  unsigned u = __float_as_uint(f);
  u = u + 0x7FFFu + ((u >> 16) & 1u);   // round-to-nearest-even
  return (unsigned short)(u >> 16);
}
__device__ __forceinline__ float bf2f(unsigned short b) {
  return __uint_as_float(((unsigned)b) << 16);
}
// add 8 bf16 (packed in uint4) into f32 acc[8] via bit-ops
__device__ __forceinline__ void addbf8(float* a, uint4 u) {
  a[0] += __uint_as_float(u.x << 16);
  a[1] += __uint_as_float(u.x & 0xFFFF0000u);
  a[2] += __uint_as_float(u.y << 16);
  a[3] += __uint_as_float(u.y & 0xFFFF0000u);
  a[4] += __uint_as_float(u.z << 16);
  a[5] += __uint_as_float(u.z & 0xFFFF0000u);
  a[6] += __uint_as_float(u.w << 16);
  a[7] += __uint_as_float(u.w & 0xFFFF0000u);
}

// K1: radix-partition edges into 128 dst-bins per t, packed (dl<<16)|src.
__global__ void k_part(const int* __restrict__ ei, int* __restrict__ bincur,
                       int* __restrict__ binbuf) {
  int t = blockIdx.y;
  int e0 = blockIdx.x * CHUNK_A;
  const int* dstp = ei + (size_t)(t * 2 + 1) * E_EDGES;
  const int* srcp = ei + (size_t)(t * 2 + 0) * E_EDGES;
  __shared__ int hist[NB], bbase[NB];
  int tid = threadIdx.x;
  for (int i = tid; i < NB; i += 256) hist[i] = 0;
  __syncthreads();
  const int4* d4 = reinterpret_cast<const int4*>(dstp + e0);
  const int4* s4 = reinterpret_cast<const int4*>(srcp + e0);
  for (int q = tid; q < CHUNK_A / 4; q += 256) {
    int4 d = d4[q];
    #pragma unroll
    for (int k = 0; k < 4; ++k) {
      int dst = (k == 0) ? d.x : (k == 1) ? d.y : (k == 2) ? d.z : d.w;
      atomicAdd(&hist[dst / NPB], 1);
    }
  }
  __syncthreads();
  for (int i = tid; i < NB; i += 256) {
    int c = hist[i];
    bbase[i] = atomicAdd(&bincur[t * NB + i], c);
    hist[i] = 0;
  }
  __syncthreads();
  for (int q = tid; q < CHUNK_A / 4; q += 256) {
    int4 d = d4[q];     // L2-hot re-read
    int4 s = s4[q];
    #pragma unroll
    for (int k = 0; k < 4; ++k) {
      int dst = (k == 0) ? d.x : (k == 1) ? d.y : (k == 2) ? d.z : d.w;
      int src = (k == 0) ? s.x : (k == 1) ? s.y : (k == 2) ? s.z : s.w;
      int b = dst / NPB;
      int dl = dst - b * NPB;
      int off = bbase[b] + atomicAdd(&hist[b], 1);
      if (off < BIN_CAP)
        binbuf[(size_t)(t * NB + b) * BIN_CAP + off] = (dl << 16) | src;
    }
  }
}

// K2: per-(t,bin) finalize: LDS stage -> per-node histogram (deg) -> block
// scan (rowg) -> in-place counting sort by local node.
__global__ void k_degfill(const int* __restrict__ bincur, int* __restrict__ binbuf,
                          int* __restrict__ deg, int* __restrict__ rowg) {
  int b = blockIdx.x & (NB - 1);
  int t = blockIdx.x >> 7;
  __shared__ int stage[BIN_CAP];        // 32KB
  __shared__ int hist[NPB], rowoff[NPB + 1];
  __shared__ int wsum[4];
  int tid = threadIdx.x;
  int cnt = bincur[t * NB + b];
  if (cnt > BIN_CAP) cnt = BIN_CAP;
  int* gbuf = binbuf + (size_t)(t * NB + b) * BIN_CAP;
  for (int i = tid; i < cnt; i += 256) stage[i] = gbuf[i];
  for (int i = tid; i < NPB; i += 256) hist[i] = 0;
  __syncthreads();
  for (int i = tid; i < cnt; i += 256) atomicAdd(&hist[stage[i] >> 16], 1);
  __syncthreads();
  int nb0 = b * NPB;
  for (int dl = tid; dl < NPB; dl += 256) {
    int n = nb0 + dl;
    if (n < N_NODES) deg[t * N_NODES + n] = hist[dl];
  }
  // block exclusive scan of hist[0..NPB)
  int i0 = 2 * tid, i1 = 2 * tid + 1;
  int a0 = (i0 < NPB) ? hist[i0] : 0;
  int a1 = (i1 < NPB) ? hist[i1] : 0;
  int tsum = a0 + a1;
  int lane = tid & 63, wid = tid >> 6;
  int sc = tsum;
  #pragma unroll
  for (int off = 1; off < 64; off <<= 1) {
    int o = __shfl_up(sc, off, 64);
    if (lane >= off) sc += o;
  }
  if (lane == 63) wsum[wid] = sc;
  __syncthreads();
  if (tid == 0) {
    int c = 0;
    for (int k = 0; k < 4; ++k) { int v = wsum[k]; wsum[k] = c; c += v; }
  }
  __syncthreads();
  int excl = wsum[wid] + (sc - tsum);
  if (i0 < NPB) rowoff[i0] = excl;
  if (i1 < NPB) rowoff[i1] = excl + a0;
  if (tid == 0) rowoff[NPB] = cnt;
  __syncthreads();
  int* rg = rowg + (size_t)(t * NB + b) * (NPB + 1);
  for (int i = tid; i <= NPB; i += 256) rg[i] = rowoff[i];
  for (int i = tid; i < NPB; i += 256) hist[i] = 0;   // reuse as cursor
  __syncthreads();
  for (int i = tid; i < cnt; i += 256) {
    int w = stage[i];
    int dl = w >> 16;
    int pos = rowoff[dl] + atomicAdd(&hist[dl], 1);
    gbuf[pos] = w & 0xFFFF;           // src only, sorted by local node
  }
}

// K3: s = rsqrt(deg+1) * (x @ conv_w), bf16. 128-node tile, 32KB LDS,
// 2 threads per node on wave-uniform k-halves.
__global__ void k_xw(const float* __restrict__ x, const float* __restrict__ w,
                     const int* __restrict__ deg, unsigned short* __restrict__ s) {
  int t = blockIdx.y;
  int bn0 = blockIdx.x * 128;
  int tid = threadIdx.x;
  __shared__ float4 xs4[128 * 16];      // 32KB: x rows, slot-swizzled
  const float4* gx4 = reinterpret_cast<const float4*>(x + ((size_t)t * N_NODES + bn0) * F_DIM);
  int nrem = N_NODES - bn0;             // may be < 128 in last block
  #pragma unroll
  for (int i = 0; i < 8; ++i) {
    int q = tid + i * 256;              // 0..2047
    int node = q >> 4, c = q & 15;
    if (node < nrem) xs4[node * 16 + (c ^ (node & 15))] = gx4[q];
  }
  __syncthreads();
  int node = tid & 127;
  int kh = __builtin_amdgcn_readfirstlane(tid >> 7);  // wave-uniform k-half
  int n = bn0 + node;
  bool act = (node < nrem);
  const float4* w4 = reinterpret_cast<const float4*>(w);
  float4 acc[8];
  #pragma unroll
  for (int h = 0; h < 8; ++h) acc[h] = make_float4(0.f, 0.f, 0.f, 0.f);
  if (act) {
    #pragma unroll
    for (int cc = 0; cc < 8; ++cc) {
      int c = kh * 8 + cc;
      float4 xv = xs4[node * 16 + (c ^ (node & 15))];
      #pragma unroll
      for (int kk = 0; kk < 4; ++kk) {
        float xsc = (kk == 0) ? xv.x : (kk == 1) ? xv.y : (kk == 2) ? xv.z : xv.w;
        int k = c * 4 + kk;
        #pragma unroll
        for (int h = 0; h < 8; ++h) {
          float4 wv = w4[k * 8 + h];    // k wave-uniform -> s_load
          acc[h].x += xsc * wv.x; acc[h].y += xsc * wv.y;
          acc[h].z += xsc * wv.z; acc[h].w += xsc * wv.w;
        }
      }
    }
  }
  __syncthreads();                      // all xs reads done; reuse buffer
  float4* pb = xs4;                     // partial sums: [128 nodes][8 h-quads]
  if (kh == 0 && act) {
    #pragma unroll
    for (int h = 0; h < 8; ++h) pb[node * 8 + (h ^ (node & 7))] = acc[h];
  }
  __syncthreads();
  if (kh == 1 && act) {
    float dinv = rsqrtf((float)(deg[t * N_NODES + n] + 1));
    unsigned short* srow = s + ((size_t)t * N_NODES + n) * H_DIM;
    #pragma unroll
    for (int h = 0; h < 8; h += 2) {
      float4 p0 = pb[node * 8 + (h ^ (node & 7))];
      float4 p1 = pb[node * 8 + ((h + 1) ^ (node & 7))];
      float4 a0 = acc[h], a1 = acc[h + 1];
      a0.x += p0.x; a0.y += p0.y; a0.z += p0.z; a0.w += p0.w;
      a1.x += p1.x; a1.y += p1.y; a1.z += p1.z; a1.w += p1.w;
      uint4 u;
      u.x = (unsigned)f2bf(a0.x * dinv) | ((unsigned)f2bf(a0.y * dinv) << 16);
      u.y = (unsigned)f2bf(a0.z * dinv) | ((unsigned)f2bf(a0.w * dinv) << 16);
      u.z = (unsigned)f2bf(a1.x * dinv) | ((unsigned)f2bf(a1.y * dinv) << 16);
      u.w = (unsigned)f2bf(a1.z * dinv) | ((unsigned)f2bf(a1.w * dinv) << 16);
      *reinterpret_cast<uint4*>(srow + h * 4) = u;
    }
  }
}

// K4: atomic-free per-node gather. 4 lanes/node (16B uint4 loads, 8 bf16
// features each) + 2-edge unrolled loop: 2x memory-level parallelism vs the
// 8B/1-edge version that was dependent-chain latency-bound at 80us.
// t = bid&7 pins each t to one XCD so the 3.2MB s-slice stays L2-resident.
__global__ void k_gather2(const unsigned short* __restrict__ s, const int* __restrict__ binsrt,
                          const int* __restrict__ rowg, const float* __restrict__ conv_b,
                          float* __restrict__ partials) {
  int bid = blockIdx.x;
  int t = bid & 7;
  int gblk = bid >> 3;                  // 0..NBLK_G2-1 (64 nodes each)
  int tid = threadIdx.x;
  int g = tid >> 2, j = tid & 3;        // 64 node-groups x 4 lanes; lane j -> feats 8j..8j+7
  int n = gblk * 64 + g;
  float acc[8];
  #pragma unroll
  for (int e = 0; e < 8; ++e) acc[e] = 0.f;
  if (n < N_NODES) {
    int b = n / NPB, dl = n - b * NPB;
    const int* ro = rowg + (size_t)(t * NB + b) * (NPB + 1);
    int start = ro[dl], end = ro[dl + 1];
    float dinv = rsqrtf((float)(end - start + 1));
    const unsigned short* sbase = s + (size_t)t * N_NODES * H_DIM;
    uint4 su = *reinterpret_cast<const uint4*>(sbase + (size_t)n * H_DIM + j * 8);
    addbf8(acc, su);                    // self-loop row
    const int* col = binsrt + (size_t)(t * NB + b) * BIN_CAP;
    int p = start;
    for (; p + 2 <= end; p += 2) {      // two independent col->row chains
      int c0 = col[p], c1 = col[p + 1];
      uint4 v0 = *reinterpret_cast<const uint4*>(sbase + (size_t)c0 * H_DIM + j * 8);
      uint4 v1 = *reinterpret_cast<const uint4*>(sbase + (size_t)c1 * H_DIM + j * 8);
      addbf8(acc, v0);
      addbf8(acc, v1);
    }
    if (p < end) {
      int c0 = col[p];
      uint4 v0 = *reinterpret_cast<const uint4*>(sbase + (size_t)c0 * H_DIM + j * 8);
      addbf8(acc, v0);
    }
    const float4* cb4 = reinterpret_cast<const float4*>(conv_b);
    float4 b0 = cb4[j * 2], b1 = cb4[j * 2 + 1];
    acc[0] = fmaxf(acc[0] * dinv + b0.x, 0.f);
    acc[1] = fmaxf(acc[1] * dinv + b0.y, 0.f);
    acc[2] = fmaxf(acc[2] * dinv + b0.z, 0.f);
    acc[3] = fmaxf(acc[3] * dinv + b0.w, 0.f);
    acc[4] = fmaxf(acc[4] * dinv + b1.x, 0.f);
    acc[5] = fmaxf(acc[5] * dinv + b1.y, 0.f);
    acc[6] = fmaxf(acc[6] * dinv + b1.z, 0.f);
    acc[7] = fmaxf(acc[7] * dinv + b1.w, 0.f);
  }
  // reduce across the 16 groups of each wave (classes = lane&3)
  #pragma unroll
  for (int off = 4; off < 64; off <<= 1) {
    #pragma unroll
    for (int e = 0; e < 8; ++e) acc[e] += __shfl_xor(acc[e], off, 64);
  }
  __shared__ float red[4][32];
  int wid = tid >> 6, lane = tid & 63;
  if (lane < 4) {
    #pragma unroll
    for (int e = 0; e < 8; ++e) red[wid][lane * 8 + e] = acc[e];
  }
  __syncthreads();
  if (tid < 32) {
    float sum = red[0][tid] + red[1][tid] + red[2][tid] + red[3][tid];
    partials[((size_t)t * NBLK_G2 + gblk) * H_DIM + tid] = sum;
  }
}

// K5: reduce per-block partials -> pooled node-sum per (t,h)
__global__ void k_reduce(const float* __restrict__ partials, float* __restrict__ seq_raw,
                         int nblk) {
  int t = blockIdx.x;
  int tid = threadIdx.x;
  int h = tid & 31, w = tid >> 5;
  float sum = 0.f;
  for (int b = w; b < nblk; b += 8) sum += partials[((size_t)t * nblk + b) * H_DIM + h];
  __shared__ float red[8][32];
  red[w][h] = sum;
  __syncthreads();
  if (tid < 32) {
    float sm = 0.f;
    #pragma unroll
    for (int i = 0; i < 8; ++i) sm += red[i][tid];
    seq_raw[t * H_DIM + tid] = sm;
  }
}

// K6: gate-x precompute (all t) + sequential LSTM + fc head, one block.
__global__ void k_lstm(const float* __restrict__ seq_raw, const float* __restrict__ w_ih,
                       const float* __restrict__ b_ih, const float* __restrict__ b_hh,
                       const float* __restrict__ w_hh, const float* __restrict__ fc_w,
                       const float* __restrict__ fc_b, float* __restrict__ out) {
  __shared__ float xb[T_DIM][32];
  __shared__ float gxs[T_DIM][256];
  __shared__ float hbuf[64], cbuf[64], gates[256];
  int j = threadIdx.x;                  // 256
  if (j < T_DIM * 32) xb[j >> 5][j & 31] = seq_raw[j] * (1.0f / (float)N_NODES);
  if (j < 64) { hbuf[j] = 0.f; cbuf[j] = 0.f; }
  __syncthreads();
  float bsum = b_ih[j] + b_hh[j];
  for (int t = 0; t < T_DIM; ++t) {
    float gacc = bsum;
    #pragma unroll
    for (int k = 0; k < 32; ++k) gacc += w_ih[j * 32 + k] * xb[t][k];
    gxs[t][j] = gacc;
  }
  __syncthreads();
  for (int t = 0; t < T_DIM; ++t) {
    float g = gxs[t][j];
    #pragma unroll 8
    for (int k = 0; k < 64; ++k) g += w_hh[j * 64 + k] * hbuf[k];
    gates[j] = g;
    __syncthreads();
    if (j < 64) {
      float ii = 1.f / (1.f + expf(-gates[j]));
      float ff = 1.f / (1.f + expf(-gates[64 + j]));
      float gg = tanhf(gates[128 + j]);
      float oo = 1.f / (1.f + expf(-gates[192 + j]));
      float c = ff * cbuf[j] + ii * gg;
      cbuf[j] = c;
      hbuf[j] = oo * tanhf(c);
    }
    __syncthreads();
  }
  if (j == 0) {
    float acc = 0.f;
    for (int k = 0; k < 64; ++k) acc += hbuf[k] * fc_w[k];
    out[0] = acc + fc_b[0];
  }
}

extern "C" void kernel_launch(void* const* d_in, const int* in_sizes, int n_in,
                              void* d_out, int out_size, void* d_ws, size_t ws_size,
                              hipStream_t stream) {
  const float* x      = (const float*)d_in[0];
  const int*   ei     = (const int*)  d_in[1];
  const float* conv_w = (const float*)d_in[2];
  const float* conv_b = (const float*)d_in[3];
  const float* w_ih   = (const float*)d_in[4];
  const float* w_hh   = (const float*)d_in[5];
  const float* b_ih   = (const float*)d_in[6];
  const float* b_hh   = (const float*)d_in[7];
  const float* fc_w   = (const float*)d_in[8];
  const float* fc_b   = (const float*)d_in[9];
  float* out = (float*)d_out;

  char* wsb = (char*)d_ws;
  size_t off = 0;
  auto alloc = [&](size_t bytes) {
    void* p = wsb + off;
    off = (off + bytes + 255) & ~(size_t)255;
    return p;
  };
  int* bincur   = (int*)alloc(sizeof(int) * T_DIM * NB);                    // 4 KB
  int* binbuf   = (int*)alloc(sizeof(int) * (size_t)T_DIM * NB * BIN_CAP);  // 32 MB
  int* deg      = (int*)alloc(sizeof(int) * T_DIM * N_NODES);               // 1.6 MB
  int* rowg     = (int*)alloc(sizeof(int) * (size_t)T_DIM * NB * (NPB + 1)); // 1.6 MB
  unsigned short* s = (unsigned short*)alloc(sizeof(unsigned short) * (size_t)T_DIM * N_NODES * H_DIM); // 25.6 MB
  float* partials = (float*)alloc(sizeof(float) * (size_t)T_DIM * NBLK_G2 * H_DIM);
  float* seq_raw  = (float*)alloc(sizeof(float) * T_DIM * H_DIM);

  (void)hipMemsetAsync(bincur, 0, sizeof(int) * T_DIM * NB, stream);

  dim3 gA(E_EDGES / CHUNK_A, T_DIM);      // 50 x 8
  k_part<<<gA, 256, 0, stream>>>(ei, bincur, binbuf);
  k_degfill<<<T_DIM * NB, 256, 0, stream>>>(bincur, binbuf, deg, rowg);
  dim3 g4((N_NODES + 127) / 128, T_DIM);  // 391 x 8
  k_xw<<<g4, 256, 0, stream>>>(x, conv_w, deg, s);
  k_gather2<<<NBLK_G2 * T_DIM, 256, 0, stream>>>(s, binbuf, rowg, conv_b, partials);
  k_reduce<<<T_DIM, 256, 0, stream>>>(partials, seq_raw, NBLK_G2);
  k_lstm<<<1, 256, 0, stream>>>(seq_raw, w_ih, b_ih, b_hh, w_hh, fc_w, fc_b, out);
}

// Round 9
// 209.742 us; speedup vs baseline: 7.0481x; 1.1298x over previous
//
#include <hip/hip_runtime.h>
#include <hip/hip_bf16.h>
#include <cstdint>
#include <cstddef>

#define T_DIM 8
#define N_NODES 50000
#define F_DIM 64
#define H_DIM 32
#define L_DIM 64
#define E_EDGES 800000

#define NB 128            // dst bins per t
#define NPB 391           // nodes per bin (128*391 = 50048 >= 50000)
#define BIN_CAP 8192      // mean 6250 + 24 sigma
#define CHUNK_A 16000     // edges per k_part block (50 blocks per t)
#define NBLK_G2 782       // ceil(N_NODES/64) node-groups per t

typedef __attribute__((ext_vector_type(8))) short short8;
typedef __attribute__((ext_vector_type(4))) float f32x4;

__device__ __forceinline__ unsigned short f2bf(float f) {
  unsigned u = __float_as_uint(f);
  u = u + 0x7FFFu + ((u >> 16) & 1u);   // round-to-nearest-even
  return (unsigned short)(u >> 16);
}
__device__ __forceinline__ float bf2f(unsigned short b) {
  return __uint_as_float(((unsigned)b) << 16);
}
// add 8 bf16 (packed in uint4) into f32 acc[8] via bit-ops
__device__ __forceinline__ void addbf8(float* a, uint4 u) {
  a[0] += __uint_as_float(u.x << 16);
  a[1] += __uint_as_float(u.x & 0xFFFF0000u);
  a[2] += __uint_as_float(u.y << 16);
  a[3] += __uint_as_float(u.y & 0xFFFF0000u);
  a[4] += __uint_as_float(u.z << 16);
  a[5] += __uint_as_float(u.z & 0xFFFF0000u);
  a[6] += __uint_as_float(u.w << 16);
  a[7] += __uint_as_float(u.w & 0xFFFF0000u);
}
__device__ __forceinline__ short8 pack8(float4 lo, float4 hi) {
  short8 r;
  r[0] = (short)f2bf(lo.x); r[1] = (short)f2bf(lo.y);
  r[2] = (short)f2bf(lo.z); r[3] = (short)f2bf(lo.w);
  r[4] = (short)f2bf(hi.x); r[5] = (short)f2bf(hi.y);
  r[6] = (short)f2bf(hi.z); r[7] = (short)f2bf(hi.w);
  return r;
}

// K1: radix-partition edges into 128 dst-bins per t, packed (dl<<16)|src.
__global__ void k_part(const int* __restrict__ ei, int* __restrict__ bincur,
                       int* __restrict__ binbuf) {
  int t = blockIdx.y;
  int e0 = blockIdx.x * CHUNK_A;
  const int* dstp = ei + (size_t)(t * 2 + 1) * E_EDGES;
  const int* srcp = ei + (size_t)(t * 2 + 0) * E_EDGES;
  __shared__ int hist[NB], bbase[NB];
  int tid = threadIdx.x;
  for (int i = tid; i < NB; i += 256) hist[i] = 0;
  __syncthreads();
  const int4* d4 = reinterpret_cast<const int4*>(dstp + e0);
  const int4* s4 = reinterpret_cast<const int4*>(srcp + e0);
  for (int q = tid; q < CHUNK_A / 4; q += 256) {
    int4 d = d4[q];
    #pragma unroll
    for (int k = 0; k < 4; ++k) {
      int dst = (k == 0) ? d.x : (k == 1) ? d.y : (k == 2) ? d.z : d.w;
      atomicAdd(&hist[dst / NPB], 1);
    }
  }
  __syncthreads();
  for (int i = tid; i < NB; i += 256) {
    int c = hist[i];
    bbase[i] = atomicAdd(&bincur[t * NB + i], c);
    hist[i] = 0;
  }
  __syncthreads();
  for (int q = tid; q < CHUNK_A / 4; q += 256) {
    int4 d = d4[q];     // L2-hot re-read
    int4 s = s4[q];
    #pragma unroll
    for (int k = 0; k < 4; ++k) {
      int dst = (k == 0) ? d.x : (k == 1) ? d.y : (k == 2) ? d.z : d.w;
      int src = (k == 0) ? s.x : (k == 1) ? s.y : (k == 2) ? s.z : s.w;
      int b = dst / NPB;
      int dl = dst - b * NPB;
      int off = bbase[b] + atomicAdd(&hist[b], 1);
      if (off < BIN_CAP)
        binbuf[(size_t)(t * NB + b) * BIN_CAP + off] = (dl << 16) | src;
    }
  }
}

// K2: per-(t,bin) finalize: LDS stage -> per-node histogram (deg) -> block
// scan (rowg) -> in-place counting sort by local node.
__global__ void k_degfill(const int* __restrict__ bincur, int* __restrict__ binbuf,
                          int* __restrict__ deg, int* __restrict__ rowg) {
  int b = blockIdx.x & (NB - 1);
  int t = blockIdx.x >> 7;
  __shared__ int stage[BIN_CAP];        // 32KB
  __shared__ int hist[NPB], rowoff[NPB + 1];
  __shared__ int wsum[4];
  int tid = threadIdx.x;
  int cnt = bincur[t * NB + b];
  if (cnt > BIN_CAP) cnt = BIN_CAP;
  int* gbuf = binbuf + (size_t)(t * NB + b) * BIN_CAP;
  for (int i = tid; i < cnt; i += 256) stage[i] = gbuf[i];
  for (int i = tid; i < NPB; i += 256) hist[i] = 0;
  __syncthreads();
  for (int i = tid; i < cnt; i += 256) atomicAdd(&hist[stage[i] >> 16], 1);
  __syncthreads();
  int nb0 = b * NPB;
  for (int dl = tid; dl < NPB; dl += 256) {
    int n = nb0 + dl;
    if (n < N_NODES) deg[t * N_NODES + n] = hist[dl];
  }
  // block exclusive scan of hist[0..NPB)
  int i0 = 2 * tid, i1 = 2 * tid + 1;
  int a0 = (i0 < NPB) ? hist[i0] : 0;
  int a1 = (i1 < NPB) ? hist[i1] : 0;
  int tsum = a0 + a1;
  int lane = tid & 63, wid = tid >> 6;
  int sc = tsum;
  #pragma unroll
  for (int off = 1; off < 64; off <<= 1) {
    int o = __shfl_up(sc, off, 64);
    if (lane >= off) sc += o;
  }
  if (lane == 63) wsum[wid] = sc;
  __syncthreads();
  if (tid == 0) {
    int c = 0;
    for (int k = 0; k < 4; ++k) { int v = wsum[k]; wsum[k] = c; c += v; }
  }
  __syncthreads();
  int excl = wsum[wid] + (sc - tsum);
  if (i0 < NPB) rowoff[i0] = excl;
  if (i1 < NPB) rowoff[i1] = excl + a0;
  if (tid == 0) rowoff[NPB] = cnt;
  __syncthreads();
  int* rg = rowg + (size_t)(t * NB + b) * (NPB + 1);
  for (int i = tid; i <= NPB; i += 256) rg[i] = rowoff[i];
  for (int i = tid; i < NPB; i += 256) hist[i] = 0;   // reuse as cursor
  __syncthreads();
  for (int i = tid; i < cnt; i += 256) {
    int w = stage[i];
    int dl = w >> 16;
    int pos = rowoff[dl] + atomicAdd(&hist[dl], 1);
    gbuf[pos] = w & 0xFFFF;           // src only, sorted by local node
  }
}

// K3: s = rsqrt(deg+1) * (x @ conv_w) via bf16 MFMA (16x16x32), bf16 out.
// One 16-node tile per wave, 4 MFMAs (2 k-halves x 2 h-halves). No LDS
// (R8 showed the scalar version VALU/latency-bound: 1024 fma/thread,
// VALUBusy 25%). A: lane holds x[node0+(l&15)][(l>>4)*8+j]; B: lane holds
// w[(l>>4)*8+j][l&15]; D: col=l&15, row=(l>>4)*4+r (verified m89 layout).
__global__ __launch_bounds__(256) void k_xw(const float* __restrict__ x,
                                            const float* __restrict__ w,
                                            const int* __restrict__ deg,
                                            unsigned short* __restrict__ s) {
  int t = blockIdx.y;
  int wave = threadIdx.x >> 6, lane = threadIdx.x & 63;
  int node0 = blockIdx.x * 64 + wave * 16;
  if (node0 >= N_NODES) return;         // 50000 = 781*64 + 16: clean tail
  int m = lane & 15, kg = lane >> 4;
  const float4* xr = reinterpret_cast<const float4*>(
      x + ((size_t)t * N_NODES + node0 + m) * F_DIM + kg * 8);
  short8 a0 = pack8(xr[0], xr[1]);      // k = kg*8 + 0..7
  short8 a1 = pack8(xr[8], xr[9]);      // k = 32 + kg*8 + 0..7
  const float* wb0 = w + (kg * 8) * H_DIM + m;
  const float* wb1 = wb0 + 32 * H_DIM;
  short8 b00, b01, b10, b11;            // b{khalf}{hhalf}
  #pragma unroll
  for (int j = 0; j < 8; ++j) {
    b00[j] = (short)f2bf(wb0[j * H_DIM]);
    b01[j] = (short)f2bf(wb0[j * H_DIM + 16]);
    b10[j] = (short)f2bf(wb1[j * H_DIM]);
    b11[j] = (short)f2bf(wb1[j * H_DIM + 16]);
  }
  f32x4 acc0 = {0.f, 0.f, 0.f, 0.f}, acc1 = {0.f, 0.f, 0.f, 0.f};
  acc0 = __builtin_amdgcn_mfma_f32_16x16x32_bf16(a0, b00, acc0, 0, 0, 0);
  acc0 = __builtin_amdgcn_mfma_f32_16x16x32_bf16(a1, b10, acc0, 0, 0, 0);
  acc1 = __builtin_amdgcn_mfma_f32_16x16x32_bf16(a0, b01, acc1, 0, 0, 0);
  acc1 = __builtin_amdgcn_mfma_f32_16x16x32_bf16(a1, b11, acc1, 0, 0, 0);
  unsigned short* sbase = s + ((size_t)t * N_NODES + node0) * H_DIM;
  #pragma unroll
  for (int r = 0; r < 4; ++r) {
    int row = kg * 4 + r;
    float dinv = rsqrtf((float)(deg[t * N_NODES + node0 + row] + 1));
    sbase[(size_t)row * H_DIM + m]      = f2bf(acc0[r] * dinv);
    sbase[(size_t)row * H_DIM + 16 + m] = f2bf(acc1[r] * dinv);
  }
}

// K4: atomic-free per-node gather. 4 lanes/node (16B uint4 loads) + 2-edge
// unroll for MLP. t = bid&7 pins each t to one XCD (s-slice L2-resident).
__global__ void k_gather2(const unsigned short* __restrict__ s, const int* __restrict__ binsrt,
                          const int* __restrict__ rowg, const float* __restrict__ conv_b,
                          float* __restrict__ partials) {
  int bid = blockIdx.x;
  int t = bid & 7;
  int gblk = bid >> 3;                  // 0..NBLK_G2-1 (64 nodes each)
  int tid = threadIdx.x;
  int g = tid >> 2, j = tid & 3;        // 64 node-groups x 4 lanes
  int n = gblk * 64 + g;
  float acc[8];
  #pragma unroll
  for (int e = 0; e < 8; ++e) acc[e] = 0.f;
  if (n < N_NODES) {
    int b = n / NPB, dl = n - b * NPB;
    const int* ro = rowg + (size_t)(t * NB + b) * (NPB + 1);
    int start = ro[dl], end = ro[dl + 1];
    float dinv = rsqrtf((float)(end - start + 1));
    const unsigned short* sbase = s + (size_t)t * N_NODES * H_DIM;
    uint4 su = *reinterpret_cast<const uint4*>(sbase + (size_t)n * H_DIM + j * 8);
    addbf8(acc, su);                    // self-loop row
    const int* col = binsrt + (size_t)(t * NB + b) * BIN_CAP;
    int p = start;
    for (; p + 2 <= end; p += 2) {      // two independent col->row chains
      int c0 = col[p], c1 = col[p + 1];
      uint4 v0 = *reinterpret_cast<const uint4*>(sbase + (size_t)c0 * H_DIM + j * 8);
      uint4 v1 = *reinterpret_cast<const uint4*>(sbase + (size_t)c1 * H_DIM + j * 8);
      addbf8(acc, v0);
      addbf8(acc, v1);
    }
    if (p < end) {
      int c0 = col[p];
      uint4 v0 = *reinterpret_cast<const uint4*>(sbase + (size_t)c0 * H_DIM + j * 8);
      addbf8(acc, v0);
    }
    const float4* cb4 = reinterpret_cast<const float4*>(conv_b);
    float4 b0 = cb4[j * 2], b1 = cb4[j * 2 + 1];
    acc[0] = fmaxf(acc[0] * dinv + b0.x, 0.f);
    acc[1] = fmaxf(acc[1] * dinv + b0.y, 0.f);
    acc[2] = fmaxf(acc[2] * dinv + b0.z, 0.f);
    acc[3] = fmaxf(acc[3] * dinv + b0.w, 0.f);
    acc[4] = fmaxf(acc[4] * dinv + b1.x, 0.f);
    acc[5] = fmaxf(acc[5] * dinv + b1.y, 0.f);
    acc[6] = fmaxf(acc[6] * dinv + b1.z, 0.f);
    acc[7] = fmaxf(acc[7] * dinv + b1.w, 0.f);
  }
  #pragma unroll
  for (int off = 4; off < 64; off <<= 1) {
    #pragma unroll
    for (int e = 0; e < 8; ++e) acc[e] += __shfl_xor(acc[e], off, 64);
  }
  __shared__ float red[4][32];
  int wid = tid >> 6, lane = tid & 63;
  if (lane < 4) {
    #pragma unroll
    for (int e = 0; e < 8; ++e) red[wid][lane * 8 + e] = acc[e];
  }
  __syncthreads();
  if (tid < 32) {
    float sum = red[0][tid] + red[1][tid] + red[2][tid] + red[3][tid];
    partials[((size_t)t * NBLK_G2 + gblk) * H_DIM + tid] = sum;
  }
}

// K5: reduce per-block partials -> pooled node-sum per (t,h)
__global__ void k_reduce(const float* __restrict__ partials, float* __restrict__ seq_raw,
                         int nblk) {
  int t = blockIdx.x;
  int tid = threadIdx.x;
  int h = tid & 31, w = tid >> 5;
  float sum = 0.f;
  for (int b = w; b < nblk; b += 8) sum += partials[((size_t)t * nblk + b) * H_DIM + h];
  __shared__ float red[8][32];
  red[w][h] = sum;
  __syncthreads();
  if (tid < 32) {
    float sm = 0.f;
    #pragma unroll
    for (int i = 0; i < 8; ++i) sm += red[i][tid];
    seq_raw[t * H_DIM + tid] = sm;
  }
}

// K6: gate-x precompute (all t) + sequential LSTM + fc head, one block.
__global__ void k_lstm(const float* __restrict__ seq_raw, const float* __restrict__ w_ih,
                       const float* __restrict__ b_ih, const float* __restrict__ b_hh,
                       const float* __restrict__ w_hh, const float* __restrict__ fc_w,
                       const float* __restrict__ fc_b, float* __restrict__ out) {
  __shared__ float xb[T_DIM][32];
  __shared__ float gxs[T_DIM][256];
  __shared__ float hbuf[64], cbuf[64], gates[256];
  int j = threadIdx.x;                  // 256
  if (j < T_DIM * 32) xb[j >> 5][j & 31] = seq_raw[j] * (1.0f / (float)N_NODES);
  if (j < 64) { hbuf[j] = 0.f; cbuf[j] = 0.f; }
  __syncthreads();
  float bsum = b_ih[j] + b_hh[j];
  for (int t = 0; t < T_DIM; ++t) {
    float gacc = bsum;
    #pragma unroll
    for (int k = 0; k < 32; ++k) gacc += w_ih[j * 32 + k] * xb[t][k];
    gxs[t][j] = gacc;
  }
  __syncthreads();
  for (int t = 0; t < T_DIM; ++t) {
    float g = gxs[t][j];
    #pragma unroll 8
    for (int k = 0; k < 64; ++k) g += w_hh[j * 64 + k] * hbuf[k];
    gates[j] = g;
    __syncthreads();
    if (j < 64) {
      float ii = 1.f / (1.f + expf(-gates[j]));
      float ff = 1.f / (1.f + expf(-gates[64 + j]));
      float gg = tanhf(gates[128 + j]);
      float oo = 1.f / (1.f + expf(-gates[192 + j]));
      float c = ff * cbuf[j] + ii * gg;
      cbuf[j] = c;
      hbuf[j] = oo * tanhf(c);
    }
    __syncthreads();
  }
  if (j == 0) {
    float acc = 0.f;
    for (int k = 0; k < 64; ++k) acc += hbuf[k] * fc_w[k];
    out[0] = acc + fc_b[0];
  }
}

extern "C" void kernel_launch(void* const* d_in, const int* in_sizes, int n_in,
                              void* d_out, int out_size, void* d_ws, size_t ws_size,
                              hipStream_t stream) {
  const float* x      = (const float*)d_in[0];
  const int*   ei     = (const int*)  d_in[1];
  const float* conv_w = (const float*)d_in[2];
  const float* conv_b = (const float*)d_in[3];
  const float* w_ih   = (const float*)d_in[4];
  const float* w_hh   = (const float*)d_in[5];
  const float* b_ih   = (const float*)d_in[6];
  const float* b_hh   = (const float*)d_in[7];
  const float* fc_w   = (const float*)d_in[8];
  const float* fc_b   = (const float*)d_in[9];
  float* out = (float*)d_out;

  char* wsb = (char*)d_ws;
  size_t off = 0;
  auto alloc = [&](size_t bytes) {
    void* p = wsb + off;
    off = (off + bytes + 255) & ~(size_t)255;
    return p;
  };
  int* bincur   = (int*)alloc(sizeof(int) * T_DIM * NB);                    // 4 KB
  int* binbuf   = (int*)alloc(sizeof(int) * (size_t)T_DIM * NB * BIN_CAP);  // 32 MB
  int* deg      = (int*)alloc(sizeof(int) * T_DIM * N_NODES);               // 1.6 MB
  int* rowg     = (int*)alloc(sizeof(int) * (size_t)T_DIM * NB * (NPB + 1)); // 1.6 MB
  unsigned short* s = (unsigned short*)alloc(sizeof(unsigned short) * (size_t)T_DIM * N_NODES * H_DIM); // 25.6 MB
  float* partials = (float*)alloc(sizeof(float) * (size_t)T_DIM * NBLK_G2 * H_DIM);
  float* seq_raw  = (float*)alloc(sizeof(float) * T_DIM * H_DIM);

  (void)hipMemsetAsync(bincur, 0, sizeof(int) * T_DIM * NB, stream);

  dim3 gA(E_EDGES / CHUNK_A, T_DIM);      // 50 x 8
  k_part<<<gA, 256, 0, stream>>>(ei, bincur, binbuf);
  k_degfill<<<T_DIM * NB, 256, 0, stream>>>(bincur, binbuf, deg, rowg);
  dim3 g4(NBLK_G2, T_DIM);                // 782 x 8, 64 nodes/block
  k_xw<<<g4, 256, 0, stream>>>(x, conv_w, deg, s);
  k_gather2<<<NBLK_G2 * T_DIM, 256, 0, stream>>>(s, binbuf, rowg, conv_b, partials);
  k_reduce<<<T_DIM, 256, 0, stream>>>(partials, seq_raw, NBLK_G2);
  k_lstm<<<1, 256, 0, stream>>>(seq_raw, w_ih, b_ih, b_hh, w_hh, fc_w, fc_b, out);
}